// Round 1
// baseline (5128.601 us; speedup 1.0000x reference)
//
#include <hip/hip_runtime.h>
#include <math.h>

#define D_MODEL 1024
#define NHEADS  16
#define HEAD_D  64
#define NTOK    4096
#define N_EXP   8
#define D_FF    4096
#define CAP     2048
#define LN_EPS  1e-5f

typedef unsigned short u16;
typedef unsigned int   u32;
typedef unsigned long long u64;

__device__ __forceinline__ float bf16_to_f32(u16 h) {
  return __uint_as_float(((u32)h) << 16);
}
__device__ __forceinline__ u16 f32_to_bf16(float f) {
  u32 u = __float_as_uint(f);
  u32 r = u + 0x7FFFu + ((u >> 16) & 1u);
  return (u16)(r >> 16);
}

// ---------------------------------------------------------------------------
// GEMM (NT): Y[m,n] = sum_k A[m,k]*W[n,k] + bias[n]
// A: MxK row-major (lda=K), W: NxK row-major (ldw=K). grid (M/64, N/64), 256 thr
// ---------------------------------------------------------------------------
__global__ __launch_bounds__(256) void gemm_nt(
    const float* __restrict__ A, const float* __restrict__ W,
    const float* __restrict__ bias, float* __restrict__ Y,
    int ldy, int K)
{
  const int m0 = blockIdx.x * 64;
  const int n0 = blockIdx.y * 64;
  __shared__ float As[16][64];
  __shared__ float Bs[16][64];
  const int t  = threadIdx.x;
  const int tx = t & 15, ty = t >> 4;
  const int r  = t >> 2, kq = t & 3;
  const float* Ap = A + (size_t)(m0 + r) * K + kq * 4;
  const float* Wp = W + (size_t)(n0 + r) * K + kq * 4;
  float acc[4][4] = {};
  for (int k0 = 0; k0 < K; k0 += 16) {
    float4 a4 = *(const float4*)(Ap + k0);
    float4 b4 = *(const float4*)(Wp + k0);
    __syncthreads();
    As[kq*4+0][r] = a4.x; As[kq*4+1][r] = a4.y;
    As[kq*4+2][r] = a4.z; As[kq*4+3][r] = a4.w;
    Bs[kq*4+0][r] = b4.x; Bs[kq*4+1][r] = b4.y;
    Bs[kq*4+2][r] = b4.z; Bs[kq*4+3][r] = b4.w;
    __syncthreads();
#pragma unroll
    for (int k = 0; k < 16; ++k) {
      float4 av = *(const float4*)&As[k][ty*4];
      float4 bv = *(const float4*)&Bs[k][tx*4];
      float aa[4] = {av.x, av.y, av.z, av.w};
      float bb[4] = {bv.x, bv.y, bv.z, bv.w};
#pragma unroll
      for (int i = 0; i < 4; ++i)
#pragma unroll
        for (int j = 0; j < 4; ++j)
          acc[i][j] = fmaf(aa[i], bb[j], acc[i][j]);
    }
  }
  float4 bv4 = *(const float4*)&bias[n0 + tx*4];
  float bb[4] = {bv4.x, bv4.y, bv4.z, bv4.w};
#pragma unroll
  for (int i = 0; i < 4; ++i) {
    float4 o;
    o.x = acc[i][0] + bb[0]; o.y = acc[i][1] + bb[1];
    o.z = acc[i][2] + bb[2]; o.w = acc[i][3] + bb[3];
    *(float4*)&Y[(size_t)(m0 + ty*4 + i) * ldy + n0 + tx*4] = o;
  }
}

// ---------------------------------------------------------------------------
// Flash attention (fp32): one (b,h) and a 32-row Q tile per block; K tiles of 64
// token t = s*2 + b. grid (Sq/32, B*NHEADS), 256 thr.
// ---------------------------------------------------------------------------
__global__ __launch_bounds__(256) void flash_attn(
    const float* __restrict__ Q, int ldq,
    const float* __restrict__ Kp, int ldk,
    const float* __restrict__ Vp, int ldv,
    float* __restrict__ O, int ldo, int Sk)
{
  const int qt = blockIdx.x;
  const int bh = blockIdx.y;
  const int b  = bh >> 4;
  const int h  = bh & 15;
  const int col = h * HEAD_D;
  __shared__ float Qs[64][36];   // [d][i], i = q-row within tile (32)
  __shared__ float Ks[64][68];   // [d][j]
  __shared__ float Vs[64][68];   // [j][d]
  __shared__ float Ss[64][36];   // [j][i]
  __shared__ float m_s[32], l_s[32], al_s[32];
  const int t  = threadIdx.x;
  const int tx = t & 15, ty = t >> 4;

#pragma unroll
  for (int p = 0; p < 2; ++p) {
    int id = t + p * 256;
    int r = id >> 4, dq = id & 15;
    int s = qt * 32 + r;
    float4 q4 = *(const float4*)&Q[(size_t)(s * 2 + b) * ldq + col + dq * 4];
    Qs[dq*4+0][r] = q4.x; Qs[dq*4+1][r] = q4.y;
    Qs[dq*4+2][r] = q4.z; Qs[dq*4+3][r] = q4.w;
  }
  if (t < 32) { m_s[t] = -1e30f; l_s[t] = 0.f; }
  float o[2][4] = {};
  for (int kt = 0; kt < Sk / 64; ++kt) {
    __syncthreads();
#pragma unroll
    for (int p = 0; p < 4; ++p) {
      int id = t + p * 256;
      int r = id >> 4, dq = id & 15;
      int sk = kt * 64 + r;
      float4 k4 = *(const float4*)&Kp[(size_t)(sk * 2 + b) * ldk + col + dq * 4];
      Ks[dq*4+0][r] = k4.x; Ks[dq*4+1][r] = k4.y;
      Ks[dq*4+2][r] = k4.z; Ks[dq*4+3][r] = k4.w;
      float4 v4 = *(const float4*)&Vp[(size_t)(sk * 2 + b) * ldv + col + dq * 4];
      *(float4*)&Vs[r][dq*4] = v4;
    }
    __syncthreads();
    // scores: rows i0=ty*2(+0..1), cols j0=tx*4(+0..3)
    float sc[2][4] = {};
#pragma unroll
    for (int d = 0; d < 64; ++d) {
      float2 a2 = *(const float2*)&Qs[d][ty*2];
      float4 b4 = *(const float4*)&Ks[d][tx*4];
      sc[0][0] = fmaf(a2.x, b4.x, sc[0][0]);
      sc[0][1] = fmaf(a2.x, b4.y, sc[0][1]);
      sc[0][2] = fmaf(a2.x, b4.z, sc[0][2]);
      sc[0][3] = fmaf(a2.x, b4.w, sc[0][3]);
      sc[1][0] = fmaf(a2.y, b4.x, sc[1][0]);
      sc[1][1] = fmaf(a2.y, b4.y, sc[1][1]);
      sc[1][2] = fmaf(a2.y, b4.z, sc[1][2]);
      sc[1][3] = fmaf(a2.y, b4.w, sc[1][3]);
    }
#pragma unroll
    for (int j = 0; j < 4; ++j) {
      Ss[tx*4+j][ty*2+0] = sc[0][j] * 0.125f;
      Ss[tx*4+j][ty*2+1] = sc[1][j] * 0.125f;
    }
    __syncthreads();
    {
      int row = t >> 3, oct = t & 7;
      float mx = -1e30f;
#pragma unroll
      for (int jj = 0; jj < 8; ++jj)
        mx = fmaxf(mx, Ss[oct*8+jj][row]);
      mx = fmaxf(mx, __shfl_xor(mx, 1));
      mx = fmaxf(mx, __shfl_xor(mx, 2));
      mx = fmaxf(mx, __shfl_xor(mx, 4));
      float m_old = m_s[row];
      float m_new = fmaxf(m_old, mx);
      float sum = 0.f;
#pragma unroll
      for (int jj = 0; jj < 8; ++jj) {
        float p = __expf(Ss[oct*8+jj][row] - m_new);
        Ss[oct*8+jj][row] = p;
        sum += p;
      }
      sum += __shfl_xor(sum, 1);
      sum += __shfl_xor(sum, 2);
      sum += __shfl_xor(sum, 4);
      if (oct == 0) {
        float al = __expf(m_old - m_new);
        al_s[row] = al;
        l_s[row]  = l_s[row] * al + sum;
        m_s[row]  = m_new;
      }
    }
    __syncthreads();
    float al0 = al_s[ty*2+0], al1 = al_s[ty*2+1];
#pragma unroll
    for (int j = 0; j < 4; ++j) { o[0][j] *= al0; o[1][j] *= al1; }
#pragma unroll
    for (int jj = 0; jj < 64; ++jj) {
      float2 p2 = *(const float2*)&Ss[jj][ty*2];
      float4 v4 = *(const float4*)&Vs[jj][tx*4];
      o[0][0] = fmaf(p2.x, v4.x, o[0][0]);
      o[0][1] = fmaf(p2.x, v4.y, o[0][1]);
      o[0][2] = fmaf(p2.x, v4.z, o[0][2]);
      o[0][3] = fmaf(p2.x, v4.w, o[0][3]);
      o[1][0] = fmaf(p2.y, v4.x, o[1][0]);
      o[1][1] = fmaf(p2.y, v4.y, o[1][1]);
      o[1][2] = fmaf(p2.y, v4.z, o[1][2]);
      o[1][3] = fmaf(p2.y, v4.w, o[1][3]);
    }
  }
  float li0 = 1.f / l_s[ty*2+0];
  float li1 = 1.f / l_s[ty*2+1];
  int s0 = qt * 32 + ty * 2;
  float4 o0 = {o[0][0]*li0, o[0][1]*li0, o[0][2]*li0, o[0][3]*li0};
  *(float4*)&O[(size_t)(s0 * 2 + b) * ldo + col + tx*4] = o0;
  float4 o1 = {o[1][0]*li1, o[1][1]*li1, o[1][2]*li1, o[1][3]*li1};
  *(float4*)&O[(size_t)((s0 + 1) * 2 + b) * ldo + col + tx*4] = o1;
}

// ---------------------------------------------------------------------------
// Gate: logits = x @ w_gate (1024x8), softmax, top-2. One wave per token.
// ---------------------------------------------------------------------------
__global__ __launch_bounds__(64) void gate_topk(
    const float* __restrict__ X, const float* __restrict__ Wg,
    int* __restrict__ idx0, int* __restrict__ idx1,
    float* __restrict__ gate1, float* __restrict__ gate2,
    float* __restrict__ probsum)
{
  const int tkn = blockIdx.x;
  const int lane = threadIdx.x;
  float acc[8] = {};
  for (int k = lane; k < D_MODEL; k += 64) {
    float xv = X[(size_t)tkn * D_MODEL + k];
    const float4* w4 = (const float4*)&Wg[k * 8];
    float4 wa = w4[0], wb = w4[1];
    acc[0] = fmaf(xv, wa.x, acc[0]); acc[1] = fmaf(xv, wa.y, acc[1]);
    acc[2] = fmaf(xv, wa.z, acc[2]); acc[3] = fmaf(xv, wa.w, acc[3]);
    acc[4] = fmaf(xv, wb.x, acc[4]); acc[5] = fmaf(xv, wb.y, acc[5]);
    acc[6] = fmaf(xv, wb.z, acc[6]); acc[7] = fmaf(xv, wb.w, acc[7]);
  }
#pragma unroll
  for (int off = 32; off > 0; off >>= 1)
#pragma unroll
    for (int e = 0; e < 8; ++e)
      acc[e] += __shfl_xor(acc[e], off);
  if (lane == 0) {
    float mx = acc[0];
#pragma unroll
    for (int e = 1; e < 8; ++e) mx = fmaxf(mx, acc[e]);
    float p[8], s = 0.f;
#pragma unroll
    for (int e = 0; e < 8; ++e) { p[e] = __expf(acc[e] - mx); s += p[e]; }
    float inv = 1.f / s;
#pragma unroll
    for (int e = 0; e < 8; ++e) p[e] *= inv;
    int e0 = 0; float p0 = p[0];
#pragma unroll
    for (int e = 1; e < 8; ++e) if (p[e] > p0) { p0 = p[e]; e0 = e; }
    int e1 = (e0 == 0) ? 1 : 0; float p1 = p[e1];
#pragma unroll
    for (int e = 0; e < 8; ++e) if (e != e0 && p[e] > p1) { p1 = p[e]; e1 = e; }
    idx0[tkn] = e0; idx1[tkn] = e1;
    gate1[tkn] = p0; gate2[tkn] = p1;
#pragma unroll
    for (int e = 0; e < 8; ++e) atomicAdd(&probsum[e], p[e]);
  }
}

// ---------------------------------------------------------------------------
// Routing scan: faithful cumsum/capacity semantics. 1 block, 8 waves (1/expert)
// ---------------------------------------------------------------------------
__global__ __launch_bounds__(512) void route_scan(
    const int* __restrict__ idx0, const int* __restrict__ idx1,
    int* __restrict__ slot1, int* __restrict__ slot2,
    int* __restrict__ list_tok, int* __restrict__ cnt_used,
    int* __restrict__ row_off, const float* __restrict__ probsum,
    float* __restrict__ aux_out)
{
  __shared__ int sh_used[8];
  __shared__ int sh_cnt1[8];
  const int e = threadIdx.x >> 6;
  const int lane = threadIdx.x & 63;
  const u64 ltmask = (1ull << lane) - 1ull;
  int run = 0;
  for (int c = 0; c < NTOK / 64; ++c) {
    int tk = c * 64 + lane;
    bool f = (idx0[tk] == e);
    u64 m = __ballot(f);
    if (f) {
      int loc = run + __popcll(m & ltmask);
      slot1[tk] = (loc < CAP) ? loc : -1;
      if (loc < CAP) list_tok[e * CAP + loc] = tk;
    }
    run += __popcll(m);
  }
  const int count1 = run;
  int run2 = 0;
  for (int c = 0; c < NTOK / 64; ++c) {
    int tk = c * 64 + lane;
    bool f = (idx1[tk] == e);
    u64 m = __ballot(f);
    if (f) {
      int loc = count1 + run2 + __popcll(m & ltmask);
      slot2[tk] = (loc < CAP) ? loc : -1;
      if (loc < CAP) list_tok[e * CAP + loc] = tk;
    }
    run2 += __popcll(m);
  }
  if (lane == 0) {
    int used = count1 + run2; if (used > CAP) used = CAP;
    sh_used[e] = used;
    sh_cnt1[e] = count1;
  }
  __syncthreads();
  if (threadIdx.x == 0) {
    int off = 0;
    float aux = 0.f;
    for (int k = 0; k < 8; ++k) {
      row_off[k]  = off;
      cnt_used[k] = sh_used[k];
      off += sh_used[k];
      aux += ((float)sh_cnt1[k] / (float)NTOK) * (probsum[k] / (float)NTOK);
    }
    aux_out[0] = 0.01f * 8.f * aux;
  }
}

// ---------------------------------------------------------------------------
// MoE FFN1: H = gelu(gather(X) @ W1[e] + b1[e]) -> bf16. grid (CAP/64, DFF/64, E)
// ---------------------------------------------------------------------------
__global__ __launch_bounds__(256) void moe_ffn1(
    const float* __restrict__ X, const int* __restrict__ list_tok,
    const float* __restrict__ W1, const float* __restrict__ B1,
    const int* __restrict__ cnt_used, const int* __restrict__ row_off,
    u16* __restrict__ Hbuf)
{
  const int e = blockIdx.z;
  const int cnt = cnt_used[e];
  const int m0 = blockIdx.x * 64;
  if (m0 >= cnt) return;
  const int n0 = blockIdx.y * 64;
  const float* W1e = W1 + (size_t)e * D_MODEL * D_FF;
  __shared__ float As[16][64];
  __shared__ float Bs[16][64];
  __shared__ int toks[64];
  const int t  = threadIdx.x;
  const int tx = t & 15, ty = t >> 4;
  const int r  = t >> 2, kq = t & 3;
  if (t < 64) toks[t] = (m0 + t < cnt) ? list_tok[e * CAP + m0 + t] : -1;
  __syncthreads();
  const int tok = toks[r];
  float acc[4][4] = {};
  for (int k0 = 0; k0 < D_MODEL; k0 += 16) {
    float4 a4 = make_float4(0.f, 0.f, 0.f, 0.f);
    if (tok >= 0)
      a4 = *(const float4*)&X[(size_t)tok * D_MODEL + k0 + kq * 4];
    float4 b4 = *(const float4*)&W1e[(size_t)(k0 + ty) * D_FF + n0 + tx * 4];
    __syncthreads();
    As[kq*4+0][r] = a4.x; As[kq*4+1][r] = a4.y;
    As[kq*4+2][r] = a4.z; As[kq*4+3][r] = a4.w;
    *(float4*)&Bs[ty][tx*4] = b4;
    __syncthreads();
#pragma unroll
    for (int k = 0; k < 16; ++k) {
      float4 av = *(const float4*)&As[k][ty*4];
      float4 bv = *(const float4*)&Bs[k][tx*4];
      float aa[4] = {av.x, av.y, av.z, av.w};
      float bb[4] = {bv.x, bv.y, bv.z, bv.w};
#pragma unroll
      for (int i = 0; i < 4; ++i)
#pragma unroll
        for (int j = 0; j < 4; ++j)
          acc[i][j] = fmaf(aa[i], bb[j], acc[i][j]);
    }
  }
  const int g0 = row_off[e];
  float4 bb4 = *(const float4*)&B1[(size_t)e * D_FF + n0 + tx*4];
  float bb[4] = {bb4.x, bb4.y, bb4.z, bb4.w};
#pragma unroll
  for (int i = 0; i < 4; ++i) {
    int m = m0 + ty*4 + i;
    if (m < cnt) {
      u16* hp = Hbuf + (size_t)(g0 + m) * D_FF + n0 + tx*4;
#pragma unroll
      for (int j = 0; j < 4; ++j) {
        float v = acc[i][j] + bb[j];
        v = 0.5f * v * (1.f + erff(v * 0.70710678118654752f));
        hp[j] = f32_to_bf16(v);
      }
    }
  }
}

// ---------------------------------------------------------------------------
// MoE FFN2: Yexp = H @ W2[e] + b2[e]. grid (CAP/64, D/64, E)
// ---------------------------------------------------------------------------
__global__ __launch_bounds__(256) void moe_ffn2(
    const u16* __restrict__ Hbuf, const float* __restrict__ W2,
    const float* __restrict__ B2, const int* __restrict__ cnt_used,
    const int* __restrict__ row_off, float* __restrict__ Yexp)
{
  const int e = blockIdx.z;
  const int cnt = cnt_used[e];
  const int m0 = blockIdx.x * 64;
  if (m0 >= cnt) return;
  const int n0 = blockIdx.y * 64;
  const int g0 = row_off[e];
  const float* W2e = W2 + (size_t)e * D_FF * D_MODEL;
  __shared__ float As[16][64];
  __shared__ float Bs[16][64];
  const int t  = threadIdx.x;
  const int tx = t & 15, ty = t >> 4;
  const int r  = t >> 2, kq = t & 3;
  const bool rvalid = (m0 + r) < cnt;
  const u16* Hrow = Hbuf + (size_t)(g0 + m0 + r) * D_FF + kq * 4;
  float acc[4][4] = {};
  for (int k0 = 0; k0 < D_FF; k0 += 16) {
    float a0 = 0.f, a1 = 0.f, a2 = 0.f, a3 = 0.f;
    if (rvalid) {
      ushort4 hv = *(const ushort4*)(Hrow + k0);
      a0 = bf16_to_f32(hv.x); a1 = bf16_to_f32(hv.y);
      a2 = bf16_to_f32(hv.z); a3 = bf16_to_f32(hv.w);
    }
    float4 b4 = *(const float4*)&W2e[(size_t)(k0 + ty) * D_MODEL + n0 + tx * 4];
    __syncthreads();
    As[kq*4+0][r] = a0; As[kq*4+1][r] = a1;
    As[kq*4+2][r] = a2; As[kq*4+3][r] = a3;
    *(float4*)&Bs[ty][tx*4] = b4;
    __syncthreads();
#pragma unroll
    for (int k = 0; k < 16; ++k) {
      float4 av = *(const float4*)&As[k][ty*4];
      float4 bv = *(const float4*)&Bs[k][tx*4];
      float aa[4] = {av.x, av.y, av.z, av.w};
      float bb[4] = {bv.x, bv.y, bv.z, bv.w};
#pragma unroll
      for (int i = 0; i < 4; ++i)
#pragma unroll
        for (int j = 0; j < 4; ++j)
          acc[i][j] = fmaf(aa[i], bb[j], acc[i][j]);
    }
  }
  float4 bb4 = *(const float4*)&B2[(size_t)e * D_MODEL + n0 + tx*4];
#pragma unroll
  for (int i = 0; i < 4; ++i) {
    int m = m0 + ty*4 + i;
    if (m < cnt) {
      float4 o = {acc[i][0]+bb4.x, acc[i][1]+bb4.y, acc[i][2]+bb4.z, acc[i][3]+bb4.w};
      *(float4*)&Yexp[(size_t)(g0 + m) * D_MODEL + n0 + tx*4] = o;
    }
  }
}

// ---------------------------------------------------------------------------
// Combine: out[t] = g1*keep1*Y[row1] + g2*keep2*Y[row2]
// ---------------------------------------------------------------------------
__global__ __launch_bounds__(256) void moe_combine(
    const float* __restrict__ Yexp,
    const int* __restrict__ idx0, const int* __restrict__ idx1,
    const int* __restrict__ slot1, const int* __restrict__ slot2,
    const float* __restrict__ gate1, const float* __restrict__ gate2,
    const int* __restrict__ row_off, float* __restrict__ out)
{
  const int tkn = blockIdx.x;
  const int c = threadIdx.x * 4;
  float4 acc = {0.f, 0.f, 0.f, 0.f};
  int s1 = slot1[tkn];
  if (s1 >= 0) {
    int rr = row_off[idx0[tkn]] + s1;
    float g = gate1[tkn];
    float4 y = *(const float4*)&Yexp[(size_t)rr * D_MODEL + c];
    acc.x += g * y.x; acc.y += g * y.y; acc.z += g * y.z; acc.w += g * y.w;
  }
  int s2 = slot2[tkn];
  if (s2 >= 0) {
    int rr = row_off[idx1[tkn]] + s2;
    float g = gate2[tkn];
    float4 y = *(const float4*)&Yexp[(size_t)rr * D_MODEL + c];
    acc.x += g * y.x; acc.y += g * y.y; acc.z += g * y.z; acc.w += g * y.w;
  }
  *(float4*)&out[(size_t)tkn * D_MODEL + c] = acc;
}

// ---------------------------------------------------------------------------
// Triple layernorm (in-place on d_out rows)
// ---------------------------------------------------------------------------
__global__ __launch_bounds__(256) void ln_triple(
    float* __restrict__ out,
    const float* __restrict__ g1, const float* __restrict__ b1,
    const float* __restrict__ g2, const float* __restrict__ b2,
    const float* __restrict__ g3, const float* __restrict__ b3)
{
  const int row = blockIdx.x;
  const int t = threadIdx.x;
  __shared__ float red[12];
  float4 x = *(float4*)&out[(size_t)row * D_MODEL + t * 4];
  const float* gs[3] = {g1, g2, g3};
  const float* bs[3] = {b1, b2, b3};
#pragma unroll
  for (int p = 0; p < 3; ++p) {
    float s = x.x + x.y + x.z + x.w;
    float q = x.x*x.x + x.y*x.y + x.z*x.z + x.w*x.w;
#pragma unroll
    for (int off = 32; off > 0; off >>= 1) {
      s += __shfl_xor(s, off);
      q += __shfl_xor(q, off);
    }
    const int wave = t >> 6, lane = t & 63;
    if (lane == 0) { red[wave*2] = s; red[wave*2+1] = q; }
    __syncthreads();
    if (t == 0) {
      red[8] = red[0] + red[2] + red[4] + red[6];
      red[9] = red[1] + red[3] + red[5] + red[7];
    }
    __syncthreads();
    float mean = red[8] * (1.f / 1024.f);
    float var  = red[9] * (1.f / 1024.f) - mean * mean;
    float rinv = rsqrtf(var + LN_EPS);
    float4 gv = *(const float4*)&gs[p][t*4];
    float4 bv = *(const float4*)&bs[p][t*4];
    x.x = (x.x - mean) * rinv * gv.x + bv.x;
    x.y = (x.y - mean) * rinv * gv.y + bv.y;
    x.z = (x.z - mean) * rinv * gv.z + bv.z;
    x.w = (x.w - mean) * rinv * gv.w + bv.w;
    __syncthreads();
  }
  *(float4*)&out[(size_t)row * D_MODEL + t * 4] = x;
}

extern "C" void kernel_launch(void* const* d_in, const int* in_sizes, int n_in,
                              void* d_out, int out_size, void* d_ws, size_t ws_size,
                              hipStream_t stream) {
  (void)in_sizes; (void)n_in; (void)out_size; (void)ws_size;
  const float* tgt      = (const float*)d_in[0];
  const float* memory   = (const float*)d_in[1];
  const float* w_qkv_sa = (const float*)d_in[2];
  const float* b_qkv_sa = (const float*)d_in[3];
  const float* w_o_sa   = (const float*)d_in[4];
  const float* b_o_sa   = (const float*)d_in[5];
  const float* w_qkv_ca = (const float*)d_in[6];
  const float* b_qkv_ca = (const float*)d_in[7];
  const float* w_o_ca   = (const float*)d_in[8];
  const float* b_o_ca   = (const float*)d_in[9];
  const float* ln1g = (const float*)d_in[10];
  const float* ln1b = (const float*)d_in[11];
  const float* ln2g = (const float*)d_in[12];
  const float* ln2b = (const float*)d_in[13];
  const float* ln3g = (const float*)d_in[14];
  const float* ln3b = (const float*)d_in[15];
  const float* w_gate = (const float*)d_in[16];
  const float* w1  = (const float*)d_in[17];
  const float* b1e = (const float*)d_in[18];
  const float* w2  = (const float*)d_in[19];
  const float* b2e = (const float*)d_in[20];
  float* out = (float*)d_out;

  // Workspace layout (floats). Overlays exploit liveness (see comments):
  //   [0          .. 12,582,912)  B_qkv (self QKV) ; later q2 (first 4.19M) + kv2
  //   [12,582,912 .. 16,777,216)  B_ao  (attn out / o2)
  //   [0          .. 16,777,216)  Hbuf  (bf16, 8192x4096)  -- after attn is done
  //   [16,777,216 .. 20,971,520)  B_x1 ; later Yexp part 1
  //   [20,971,520 .. 25,165,824)  B_x2 ; later Yexp part 2
  //   [25,165,824 .. )            small routing arrays
  float* ws     = (float*)d_ws;
  float* B_qkv  = ws;
  float* B_ao   = ws + 12582912;
  float* B_x1   = ws + 16777216;
  float* B_x2   = ws + 20971520;
  u16*   Hbuf   = (u16*)ws;          // overlays B_qkv + B_ao (dead by then)
  float* Yexp   = B_x1;              // overlays B_x1 + B_x2 (dead by then)
  float* q2     = B_qkv;
  float* kv2    = B_qkv + 4194304;
  int*   idx0     = (int*)(ws + 25165824);
  int*   idx1     = idx0 + NTOK;
  int*   slot1    = idx1 + NTOK;
  int*   slot2    = slot1 + NTOK;
  int*   list_tok = slot2 + NTOK;        // 8*2048
  int*   cnt_used = list_tok + N_EXP * CAP;
  int*   row_off  = cnt_used + N_EXP;
  float* gate1    = (float*)(row_off + N_EXP);
  float* gate2    = gate1 + NTOK;
  float* probsum  = gate2 + NTOK;        // 8 floats

  hipMemsetAsync(probsum, 0, N_EXP * sizeof(float), stream);

  // ---- self attention ----
  gemm_nt<<<dim3(64, 48), 256, 0, stream>>>(tgt, w_qkv_sa, b_qkv_sa, B_qkv, 3072, 1024);
  flash_attn<<<dim3(64, 32), 256, 0, stream>>>(B_qkv, 3072, B_qkv + 1024, 3072,
                                               B_qkv + 2048, 3072, B_ao, 1024, 2048);
  gemm_nt<<<dim3(64, 16), 256, 0, stream>>>(B_ao, w_o_sa, b_o_sa, B_x1, 1024, 1024);

  // ---- cross attention ----
  gemm_nt<<<dim3(64, 16), 256, 0, stream>>>(B_x1, w_qkv_ca, b_qkv_ca, q2, 1024, 1024);
  gemm_nt<<<dim3(64, 32), 256, 0, stream>>>(memory, w_qkv_ca + (size_t)1024 * 1024,
                                            b_qkv_ca + 1024, kv2, 2048, 1024);
  flash_attn<<<dim3(64, 32), 256, 0, stream>>>(q2, 1024, kv2, 2048,
                                               kv2 + 1024, 2048, B_ao, 1024, 2048);
  gemm_nt<<<dim3(64, 16), 256, 0, stream>>>(B_ao, w_o_ca, b_o_ca, B_x2, 1024, 1024);

  // ---- MoE ----
  gate_topk<<<NTOK, 64, 0, stream>>>(B_x2, w_gate, idx0, idx1, gate1, gate2, probsum);
  route_scan<<<1, 512, 0, stream>>>(idx0, idx1, slot1, slot2, list_tok, cnt_used,
                                    row_off, probsum, out + (size_t)NTOK * D_MODEL);
  moe_ffn1<<<dim3(32, 64, 8), 256, 0, stream>>>(B_x2, list_tok, w1, b1e,
                                                cnt_used, row_off, Hbuf);
  moe_ffn2<<<dim3(32, 16, 8), 256, 0, stream>>>(Hbuf, w2, b2e, cnt_used, row_off, Yexp);
  moe_combine<<<NTOK, 256, 0, stream>>>(Yexp, idx0, idx1, slot1, slot2,
                                        gate1, gate2, row_off, out);

  // ---- 3x layernorm ----
  ln_triple<<<NTOK, 256, 0, stream>>>(out, ln1g, ln1b, ln2g, ln2b, ln3g, ln3b);
}

// Round 2
// 3666.719 us; speedup vs baseline: 1.3987x; 1.3987x over previous
//
#include <hip/hip_runtime.h>
#include <math.h>

#define D_MODEL 1024
#define NHEADS  16
#define HEAD_D  64
#define NTOK    4096
#define N_EXP   8
#define D_FF    4096
#define CAP     2048
#define LN_EPS  1e-5f

typedef unsigned short u16;
typedef unsigned int   u32;
typedef unsigned long long u64;

typedef __attribute__((ext_vector_type(8))) short bf16x8;
typedef __attribute__((ext_vector_type(4))) float f32x4;

__device__ __forceinline__ float bf16_to_f32(u16 h) {
  return __uint_as_float(((u32)h) << 16);
}
__device__ __forceinline__ u16 f32_to_bf16(float f) {
  u32 u = __float_as_uint(f);
  u32 r = u + 0x7FFFu + ((u >> 16) & 1u);
  return (u16)(r >> 16);
}

// async 16B global -> LDS (lds dest must be wave-uniform base + lane*16)
__device__ __forceinline__ void gld16(const u16* g, u16* l) {
  __builtin_amdgcn_global_load_lds(
      (const __attribute__((address_space(1))) unsigned int*)g,
      (__attribute__((address_space(3))) unsigned int*)l, 16, 0, 0);
}

// ---------------------------------------------------------------------------
// fp32 GEMM (NT): Y[m,n] = sum_k A[m,k]*W[n,k] + bias[n]   (attention path)
// ---------------------------------------------------------------------------
__global__ __launch_bounds__(256) void gemm_nt(
    const float* __restrict__ A, const float* __restrict__ W,
    const float* __restrict__ bias, float* __restrict__ Y,
    int ldy, int K)
{
  const int m0 = blockIdx.x * 64;
  const int n0 = blockIdx.y * 64;
  __shared__ float As[16][64];
  __shared__ float Bs[16][64];
  const int t  = threadIdx.x;
  const int tx = t & 15, ty = t >> 4;
  const int r  = t >> 2, kq = t & 3;
  const float* Ap = A + (size_t)(m0 + r) * K + kq * 4;
  const float* Wp = W + (size_t)(n0 + r) * K + kq * 4;
  float acc[4][4] = {};
  for (int k0 = 0; k0 < K; k0 += 16) {
    float4 a4 = *(const float4*)(Ap + k0);
    float4 b4 = *(const float4*)(Wp + k0);
    __syncthreads();
    As[kq*4+0][r] = a4.x; As[kq*4+1][r] = a4.y;
    As[kq*4+2][r] = a4.z; As[kq*4+3][r] = a4.w;
    Bs[kq*4+0][r] = b4.x; Bs[kq*4+1][r] = b4.y;
    Bs[kq*4+2][r] = b4.z; Bs[kq*4+3][r] = b4.w;
    __syncthreads();
#pragma unroll
    for (int k = 0; k < 16; ++k) {
      float4 av = *(const float4*)&As[k][ty*4];
      float4 bv = *(const float4*)&Bs[k][tx*4];
      float aa[4] = {av.x, av.y, av.z, av.w};
      float bb[4] = {bv.x, bv.y, bv.z, bv.w};
#pragma unroll
      for (int i = 0; i < 4; ++i)
#pragma unroll
        for (int j = 0; j < 4; ++j)
          acc[i][j] = fmaf(aa[i], bb[j], acc[i][j]);
    }
  }
  float4 bv4 = *(const float4*)&bias[n0 + tx*4];
  float bb[4] = {bv4.x, bv4.y, bv4.z, bv4.w};
#pragma unroll
  for (int i = 0; i < 4; ++i) {
    float4 o;
    o.x = acc[i][0] + bb[0]; o.y = acc[i][1] + bb[1];
    o.z = acc[i][2] + bb[2]; o.w = acc[i][3] + bb[3];
    *(float4*)&Y[(size_t)(m0 + ty*4 + i) * ldy + n0 + tx*4] = o;
  }
}

// ---------------------------------------------------------------------------
// Flash attention (fp32)
// ---------------------------------------------------------------------------
__global__ __launch_bounds__(256) void flash_attn(
    const float* __restrict__ Q, int ldq,
    const float* __restrict__ Kp, int ldk,
    const float* __restrict__ Vp, int ldv,
    float* __restrict__ O, int ldo, int Sk)
{
  const int qt = blockIdx.x;
  const int bh = blockIdx.y;
  const int b  = bh >> 4;
  const int h  = bh & 15;
  const int col = h * HEAD_D;
  __shared__ float Qs[64][36];
  __shared__ float Ks[64][68];
  __shared__ float Vs[64][68];
  __shared__ float Ss[64][36];
  __shared__ float m_s[32], l_s[32], al_s[32];
  const int t  = threadIdx.x;
  const int tx = t & 15, ty = t >> 4;

#pragma unroll
  for (int p = 0; p < 2; ++p) {
    int id = t + p * 256;
    int r = id >> 4, dq = id & 15;
    int s = qt * 32 + r;
    float4 q4 = *(const float4*)&Q[(size_t)(s * 2 + b) * ldq + col + dq * 4];
    Qs[dq*4+0][r] = q4.x; Qs[dq*4+1][r] = q4.y;
    Qs[dq*4+2][r] = q4.z; Qs[dq*4+3][r] = q4.w;
  }
  if (t < 32) { m_s[t] = -1e30f; l_s[t] = 0.f; }
  float o[2][4] = {};
  for (int kt = 0; kt < Sk / 64; ++kt) {
    __syncthreads();
#pragma unroll
    for (int p = 0; p < 4; ++p) {
      int id = t + p * 256;
      int r = id >> 4, dq = id & 15;
      int sk = kt * 64 + r;
      float4 k4 = *(const float4*)&Kp[(size_t)(sk * 2 + b) * ldk + col + dq * 4];
      Ks[dq*4+0][r] = k4.x; Ks[dq*4+1][r] = k4.y;
      Ks[dq*4+2][r] = k4.z; Ks[dq*4+3][r] = k4.w;
      float4 v4 = *(const float4*)&Vp[(size_t)(sk * 2 + b) * ldv + col + dq * 4];
      *(float4*)&Vs[r][dq*4] = v4;
    }
    __syncthreads();
    float sc[2][4] = {};
#pragma unroll
    for (int d = 0; d < 64; ++d) {
      float2 a2 = *(const float2*)&Qs[d][ty*2];
      float4 b4 = *(const float4*)&Ks[d][tx*4];
      sc[0][0] = fmaf(a2.x, b4.x, sc[0][0]);
      sc[0][1] = fmaf(a2.x, b4.y, sc[0][1]);
      sc[0][2] = fmaf(a2.x, b4.z, sc[0][2]);
      sc[0][3] = fmaf(a2.x, b4.w, sc[0][3]);
      sc[1][0] = fmaf(a2.y, b4.x, sc[1][0]);
      sc[1][1] = fmaf(a2.y, b4.y, sc[1][1]);
      sc[1][2] = fmaf(a2.y, b4.z, sc[1][2]);
      sc[1][3] = fmaf(a2.y, b4.w, sc[1][3]);
    }
#pragma unroll
    for (int j = 0; j < 4; ++j) {
      Ss[tx*4+j][ty*2+0] = sc[0][j] * 0.125f;
      Ss[tx*4+j][ty*2+1] = sc[1][j] * 0.125f;
    }
    __syncthreads();
    {
      int row = t >> 3, oct = t & 7;
      float mx = -1e30f;
#pragma unroll
      for (int jj = 0; jj < 8; ++jj)
        mx = fmaxf(mx, Ss[oct*8+jj][row]);
      mx = fmaxf(mx, __shfl_xor(mx, 1));
      mx = fmaxf(mx, __shfl_xor(mx, 2));
      mx = fmaxf(mx, __shfl_xor(mx, 4));
      float m_old = m_s[row];
      float m_new = fmaxf(m_old, mx);
      float sum = 0.f;
#pragma unroll
      for (int jj = 0; jj < 8; ++jj) {
        float p = __expf(Ss[oct*8+jj][row] - m_new);
        Ss[oct*8+jj][row] = p;
        sum += p;
      }
      sum += __shfl_xor(sum, 1);
      sum += __shfl_xor(sum, 2);
      sum += __shfl_xor(sum, 4);
      if (oct == 0) {
        float al = __expf(m_old - m_new);
        al_s[row] = al;
        l_s[row]  = l_s[row] * al + sum;
        m_s[row]  = m_new;
      }
    }
    __syncthreads();
    float al0 = al_s[ty*2+0], al1 = al_s[ty*2+1];
#pragma unroll
    for (int j = 0; j < 4; ++j) { o[0][j] *= al0; o[1][j] *= al1; }
#pragma unroll
    for (int jj = 0; jj < 64; ++jj) {
      float2 p2 = *(const float2*)&Ss[jj][ty*2];
      float4 v4 = *(const float4*)&Vs[jj][tx*4];
      o[0][0] = fmaf(p2.x, v4.x, o[0][0]);
      o[0][1] = fmaf(p2.x, v4.y, o[0][1]);
      o[0][2] = fmaf(p2.x, v4.z, o[0][2]);
      o[0][3] = fmaf(p2.x, v4.w, o[0][3]);
      o[1][0] = fmaf(p2.y, v4.x, o[1][0]);
      o[1][1] = fmaf(p2.y, v4.y, o[1][1]);
      o[1][2] = fmaf(p2.y, v4.z, o[1][2]);
      o[1][3] = fmaf(p2.y, v4.w, o[1][3]);
    }
  }
  float li0 = 1.f / l_s[ty*2+0];
  float li1 = 1.f / l_s[ty*2+1];
  int s0 = qt * 32 + ty * 2;
  float4 o0 = {o[0][0]*li0, o[0][1]*li0, o[0][2]*li0, o[0][3]*li0};
  *(float4*)&O[(size_t)(s0 * 2 + b) * ldo + col + tx*4] = o0;
  float4 o1 = {o[1][0]*li1, o[1][1]*li1, o[1][2]*li1, o[1][3]*li1};
  *(float4*)&O[(size_t)((s0 + 1) * 2 + b) * ldo + col + tx*4] = o1;
}

// ---------------------------------------------------------------------------
// Gate: logits = x @ w_gate (1024x8), softmax, top-2. One wave per token.
// ---------------------------------------------------------------------------
__global__ __launch_bounds__(64) void gate_topk(
    const float* __restrict__ X, const float* __restrict__ Wg,
    int* __restrict__ idx0, int* __restrict__ idx1,
    float* __restrict__ gate1, float* __restrict__ gate2,
    float* __restrict__ probsum)
{
  const int tkn = blockIdx.x;
  const int lane = threadIdx.x;
  float acc[8] = {};
  for (int k = lane; k < D_MODEL; k += 64) {
    float xv = X[(size_t)tkn * D_MODEL + k];
    const float4* w4 = (const float4*)&Wg[k * 8];
    float4 wa = w4[0], wb = w4[1];
    acc[0] = fmaf(xv, wa.x, acc[0]); acc[1] = fmaf(xv, wa.y, acc[1]);
    acc[2] = fmaf(xv, wa.z, acc[2]); acc[3] = fmaf(xv, wa.w, acc[3]);
    acc[4] = fmaf(xv, wb.x, acc[4]); acc[5] = fmaf(xv, wb.y, acc[5]);
    acc[6] = fmaf(xv, wb.z, acc[6]); acc[7] = fmaf(xv, wb.w, acc[7]);
  }
#pragma unroll
  for (int off = 32; off > 0; off >>= 1)
#pragma unroll
    for (int e = 0; e < 8; ++e)
      acc[e] += __shfl_xor(acc[e], off);
  if (lane == 0) {
    float mx = acc[0];
#pragma unroll
    for (int e = 1; e < 8; ++e) mx = fmaxf(mx, acc[e]);
    float p[8], s = 0.f;
#pragma unroll
    for (int e = 0; e < 8; ++e) { p[e] = __expf(acc[e] - mx); s += p[e]; }
    float inv = 1.f / s;
#pragma unroll
    for (int e = 0; e < 8; ++e) p[e] *= inv;
    int e0 = 0; float p0 = p[0];
#pragma unroll
    for (int e = 1; e < 8; ++e) if (p[e] > p0) { p0 = p[e]; e0 = e; }
    int e1 = (e0 == 0) ? 1 : 0; float p1 = p[e1];
#pragma unroll
    for (int e = 0; e < 8; ++e) if (e != e0 && p[e] > p1) { p1 = p[e]; e1 = e; }
    idx0[tkn] = e0; idx1[tkn] = e1;
    gate1[tkn] = p0; gate2[tkn] = p1;
#pragma unroll
    for (int e = 0; e < 8; ++e) atomicAdd(&probsum[e], p[e]);
  }
}

// ---------------------------------------------------------------------------
// Routing scan: faithful cumsum/capacity semantics. 1 block, 8 waves (1/expert)
// ---------------------------------------------------------------------------
__global__ __launch_bounds__(512) void route_scan(
    const int* __restrict__ idx0, const int* __restrict__ idx1,
    int* __restrict__ slot1, int* __restrict__ slot2,
    int* __restrict__ list_tok, int* __restrict__ cnt_used,
    int* __restrict__ row_off, const float* __restrict__ probsum,
    float* __restrict__ aux_out)
{
  __shared__ int sh_used[8];
  __shared__ int sh_cnt1[8];
  const int e = threadIdx.x >> 6;
  const int lane = threadIdx.x & 63;
  const u64 ltmask = (1ull << lane) - 1ull;
  int run = 0;
  for (int c = 0; c < NTOK / 64; ++c) {
    int tk = c * 64 + lane;
    bool f = (idx0[tk] == e);
    u64 m = __ballot(f);
    if (f) {
      int loc = run + __popcll(m & ltmask);
      slot1[tk] = (loc < CAP) ? loc : -1;
      if (loc < CAP) list_tok[e * CAP + loc] = tk;
    }
    run += __popcll(m);
  }
  const int count1 = run;
  int run2 = 0;
  for (int c = 0; c < NTOK / 64; ++c) {
    int tk = c * 64 + lane;
    bool f = (idx1[tk] == e);
    u64 m = __ballot(f);
    if (f) {
      int loc = count1 + run2 + __popcll(m & ltmask);
      slot2[tk] = (loc < CAP) ? loc : -1;
      if (loc < CAP) list_tok[e * CAP + loc] = tk;
    }
    run2 += __popcll(m);
  }
  if (lane == 0) {
    int used = count1 + run2; if (used > CAP) used = CAP;
    sh_used[e] = used;
    sh_cnt1[e] = count1;
  }
  __syncthreads();
  if (threadIdx.x == 0) {
    int off = 0;
    float aux = 0.f;
    for (int k = 0; k < 8; ++k) {
      row_off[k]  = off;
      cnt_used[k] = sh_used[k];
      off += sh_used[k];
      aux += ((float)sh_cnt1[k] / (float)NTOK) * (probsum[k] / (float)NTOK);
    }
    aux_out[0] = 0.01f * 8.f * aux;
  }
}

// ---------------------------------------------------------------------------
// Transpose + fp32->bf16: in [R][C] -> out [C][R]  (per blockIdx.z matrix)
// ---------------------------------------------------------------------------
__global__ __launch_bounds__(256) void transpose_bf16(
    const float* __restrict__ in, u16* __restrict__ outp, int R, int C)
{
  __shared__ u16 tile[32][33];
  const size_t mat = (size_t)blockIdx.z * R * C;
  const int c0 = blockIdx.x * 32, r0 = blockIdx.y * 32;
  const int t = threadIdx.x;
  {
    int r = t >> 3, cq = (t & 7) * 4;
    float4 v = *(const float4*)&in[mat + (size_t)(r0 + r) * C + c0 + cq];
    tile[r][cq+0] = f32_to_bf16(v.x);
    tile[r][cq+1] = f32_to_bf16(v.y);
    tile[r][cq+2] = f32_to_bf16(v.z);
    tile[r][cq+3] = f32_to_bf16(v.w);
  }
  __syncthreads();
  {
    int c = t >> 3, rq = (t & 7) * 4;
    ushort4 ov;
    ov.x = tile[rq+0][c]; ov.y = tile[rq+1][c];
    ov.z = tile[rq+2][c]; ov.w = tile[rq+3][c];
    *(ushort4*)&outp[mat + (size_t)(c0 + c) * R + r0 + rq] = ov;
  }
}

// ---------------------------------------------------------------------------
// Gather routed tokens -> packed bf16 rows Xg[g0+m][1024]
// ---------------------------------------------------------------------------
__global__ __launch_bounds__(256) void moe_gather(
    const float* __restrict__ X, const int* __restrict__ list_tok,
    const int* __restrict__ cnt_used, const int* __restrict__ row_off,
    u16* __restrict__ Xg)
{
  const int e = blockIdx.y;
  const int m = blockIdx.x;
  if (m >= cnt_used[e]) return;
  const int tok = list_tok[e * CAP + m];
  const int g = row_off[e] + m;
  const int c = threadIdx.x * 4;
  float4 v = *(const float4*)&X[(size_t)tok * D_MODEL + c];
  ushort4 o;
  o.x = f32_to_bf16(v.x); o.y = f32_to_bf16(v.y);
  o.z = f32_to_bf16(v.z); o.w = f32_to_bf16(v.w);
  *(ushort4*)&Xg[(size_t)g * D_MODEL + c] = o;
}

// ---------------------------------------------------------------------------
// MFMA FFN1: H = gelu(Xg @ W1T^T + b1) -> bf16. 128x128 tile, BK=64.
// grid (CAP/128, DFF/128, E), 256 thr (4 waves, 2x2 of 64x64).
// LDS chunk XOR-swizzle: row r, 16B-chunk c stored at c^(r&7).
// ---------------------------------------------------------------------------
__global__ __launch_bounds__(256) void ffn1_mfma(
    const u16* __restrict__ Xg, const u16* __restrict__ W1T,
    const float* __restrict__ B1,
    const int* __restrict__ cnt_used, const int* __restrict__ row_off,
    u16* __restrict__ Hbuf)
{
  const int e = blockIdx.z;
  const int cnt = cnt_used[e];
  const int m0 = blockIdx.x * 128;
  if (m0 >= cnt) return;
  const int n0 = blockIdx.y * 128;
  const int g0 = row_off[e];
  __shared__ __align__(16) u16 As[128 * 64];
  __shared__ __align__(16) u16 Bs[128 * 64];
  const int t = threadIdx.x;
  const int lane = t & 63;
  const int wm = ((t >> 6) & 1) * 64;
  const int wn = ((t >> 6) >> 1) * 64;
  const u16* Ab = Xg + (size_t)(g0 + m0) * D_MODEL;
  const u16* Bb = W1T + (size_t)e * ((size_t)D_FF * D_MODEL) + (size_t)n0 * D_MODEL;
  f32x4 acc[4][4] = {};
  int srow[4], scol[4];
#pragma unroll
  for (int i = 0; i < 4; ++i) {
    int id = t + i * 256;
    srow[i] = id >> 3;
    scol[i] = (id & 7) ^ (srow[i] & 7);
  }
  for (int k0 = 0; k0 < D_MODEL; k0 += 64) {
    __syncthreads();
#pragma unroll
    for (int i = 0; i < 4; ++i) {
      int r  = srow[i];
      int ra = (m0 + r < cnt) ? r : 0;     // clamp pad rows into valid region
      gld16(Ab + (size_t)ra * D_MODEL + k0 + scol[i] * 8, &As[(t + i*256) * 8]);
      gld16(Bb + (size_t)r  * D_MODEL + k0 + scol[i] * 8, &Bs[(t + i*256) * 8]);
    }
    __syncthreads();
#pragma unroll
    for (int ks = 0; ks < 2; ++ks) {
      bf16x8 af[4], bfr[4];
      const int q = ks * 4 + (lane >> 4);
#pragma unroll
      for (int i = 0; i < 4; ++i) {
        int m = wm + i * 16 + (lane & 15);
        af[i]  = *(const bf16x8*)&As[m * 64 + ((q ^ (m & 7)) * 8)];
        int n = wn + i * 16 + (lane & 15);
        bfr[i] = *(const bf16x8*)&Bs[n * 64 + ((q ^ (n & 7)) * 8)];
      }
#pragma unroll
      for (int mi = 0; mi < 4; ++mi)
#pragma unroll
        for (int ni = 0; ni < 4; ++ni)
          acc[mi][ni] = __builtin_amdgcn_mfma_f32_16x16x32_bf16(
              af[mi], bfr[ni], acc[mi][ni], 0, 0, 0);
    }
  }
  float bias_n[4];
  const int ncol = n0 + wn + (lane & 15);
#pragma unroll
  for (int ni = 0; ni < 4; ++ni)
    bias_n[ni] = B1[e * D_FF + ncol + ni * 16];
  const int rbase = m0 + wm + (lane >> 4) * 4;
#pragma unroll
  for (int mi = 0; mi < 4; ++mi) {
#pragma unroll
    for (int rg = 0; rg < 4; ++rg) {
      int m = rbase + mi * 16 + rg;
      if (m < cnt) {
        u16* hp = Hbuf + (size_t)(g0 + m) * D_FF + ncol;
#pragma unroll
        for (int ni = 0; ni < 4; ++ni) {
          float v = acc[mi][ni][rg] + bias_n[ni];
          v = 0.5f * v * (1.f + erff(v * 0.70710678118654752f));
          hp[ni * 16] = f32_to_bf16(v);
        }
      }
    }
  }
}

// ---------------------------------------------------------------------------
// MFMA FFN2: Yexp = Hbuf @ W2T^T + b2 (fp32 out). grid (CAP/128, D/128, E).
// ---------------------------------------------------------------------------
__global__ __launch_bounds__(256) void ffn2_mfma(
    const u16* __restrict__ Hbuf, const u16* __restrict__ W2T,
    const float* __restrict__ B2,
    const int* __restrict__ cnt_used, const int* __restrict__ row_off,
    float* __restrict__ Yexp)
{
  const int e = blockIdx.z;
  const int cnt = cnt_used[e];
  const int m0 = blockIdx.x * 128;
  if (m0 >= cnt) return;
  const int n0 = blockIdx.y * 128;
  const int g0 = row_off[e];
  __shared__ __align__(16) u16 As[128 * 64];
  __shared__ __align__(16) u16 Bs[128 * 64];
  const int t = threadIdx.x;
  const int lane = t & 63;
  const int wm = ((t >> 6) & 1) * 64;
  const int wn = ((t >> 6) >> 1) * 64;
  const u16* Ab = Hbuf + (size_t)(g0 + m0) * D_FF;
  const u16* Bb = W2T + (size_t)e * ((size_t)D_MODEL * D_FF) + (size_t)n0 * D_FF;
  f32x4 acc[4][4] = {};
  int srow[4], scol[4];
#pragma unroll
  for (int i = 0; i < 4; ++i) {
    int id = t + i * 256;
    srow[i] = id >> 3;
    scol[i] = (id & 7) ^ (srow[i] & 7);
  }
  for (int k0 = 0; k0 < D_FF; k0 += 64) {
    __syncthreads();
#pragma unroll
    for (int i = 0; i < 4; ++i) {
      int r  = srow[i];
      int ra = (m0 + r < cnt) ? r : 0;
      gld16(Ab + (size_t)ra * D_FF + k0 + scol[i] * 8, &As[(t + i*256) * 8]);
      gld16(Bb + (size_t)r  * D_FF + k0 + scol[i] * 8, &Bs[(t + i*256) * 8]);
    }
    __syncthreads();
#pragma unroll
    for (int ks = 0; ks < 2; ++ks) {
      bf16x8 af[4], bfr[4];
      const int q = ks * 4 + (lane >> 4);
#pragma unroll
      for (int i = 0; i < 4; ++i) {
        int m = wm + i * 16 + (lane & 15);
        af[i]  = *(const bf16x8*)&As[m * 64 + ((q ^ (m & 7)) * 8)];
        int n = wn + i * 16 + (lane & 15);
        bfr[i] = *(const bf16x8*)&Bs[n * 64 + ((q ^ (n & 7)) * 8)];
      }
#pragma unroll
      for (int mi = 0; mi < 4; ++mi)
#pragma unroll
        for (int ni = 0; ni < 4; ++ni)
          acc[mi][ni] = __builtin_amdgcn_mfma_f32_16x16x32_bf16(
              af[mi], bfr[ni], acc[mi][ni], 0, 0, 0);
    }
  }
  float bias_n[4];
  const int ncol = n0 + wn + (lane & 15);
#pragma unroll
  for (int ni = 0; ni < 4; ++ni)
    bias_n[ni] = B2[e * D_MODEL + ncol + ni * 16];
  const int rbase = m0 + wm + (lane >> 4) * 4;
#pragma unroll
  for (int mi = 0; mi < 4; ++mi) {
#pragma unroll
    for (int rg = 0; rg < 4; ++rg) {
      int m = rbase + mi * 16 + rg;
      if (m < cnt) {
        float* yp = Yexp + (size_t)(g0 + m) * D_MODEL + ncol;
#pragma unroll
        for (int ni = 0; ni < 4; ++ni)
          yp[ni * 16] = acc[mi][ni][rg] + bias_n[ni];
      }
    }
  }
}

// ---------------------------------------------------------------------------
// Fallback fp32 MoE FFN kernels (used only if ws_size is too small)
// ---------------------------------------------------------------------------
__global__ __launch_bounds__(256) void moe_ffn1(
    const float* __restrict__ X, const int* __restrict__ list_tok,
    const float* __restrict__ W1, const float* __restrict__ B1,
    const int* __restrict__ cnt_used, const int* __restrict__ row_off,
    u16* __restrict__ Hbuf)
{
  const int e = blockIdx.z;
  const int cnt = cnt_used[e];
  const int m0 = blockIdx.x * 64;
  if (m0 >= cnt) return;
  const int n0 = blockIdx.y * 64;
  const float* W1e = W1 + (size_t)e * D_MODEL * D_FF;
  __shared__ float As[16][64];
  __shared__ float Bs[16][64];
  __shared__ int toks[64];
  const int t  = threadIdx.x;
  const int tx = t & 15, ty = t >> 4;
  const int r  = t >> 2, kq = t & 3;
  if (t < 64) toks[t] = (m0 + t < cnt) ? list_tok[e * CAP + m0 + t] : -1;
  __syncthreads();
  const int tok = toks[r];
  float acc[4][4] = {};
  for (int k0 = 0; k0 < D_MODEL; k0 += 16) {
    float4 a4 = make_float4(0.f, 0.f, 0.f, 0.f);
    if (tok >= 0)
      a4 = *(const float4*)&X[(size_t)tok * D_MODEL + k0 + kq * 4];
    float4 b4 = *(const float4*)&W1e[(size_t)(k0 + ty) * D_FF + n0 + tx * 4];
    __syncthreads();
    As[kq*4+0][r] = a4.x; As[kq*4+1][r] = a4.y;
    As[kq*4+2][r] = a4.z; As[kq*4+3][r] = a4.w;
    *(float4*)&Bs[ty][tx*4] = b4;
    __syncthreads();
#pragma unroll
    for (int k = 0; k < 16; ++k) {
      float4 av = *(const float4*)&As[k][ty*4];
      float4 bv = *(const float4*)&Bs[k][tx*4];
      float aa[4] = {av.x, av.y, av.z, av.w};
      float bb[4] = {bv.x, bv.y, bv.z, bv.w};
#pragma unroll
      for (int i = 0; i < 4; ++i)
#pragma unroll
        for (int j = 0; j < 4; ++j)
          acc[i][j] = fmaf(aa[i], bb[j], acc[i][j]);
    }
  }
  const int g0 = row_off[e];
  float4 bb4 = *(const float4*)&B1[(size_t)e * D_FF + n0 + tx*4];
  float bb[4] = {bb4.x, bb4.y, bb4.z, bb4.w};
#pragma unroll
  for (int i = 0; i < 4; ++i) {
    int m = m0 + ty*4 + i;
    if (m < cnt) {
      u16* hp = Hbuf + (size_t)(g0 + m) * D_FF + n0 + tx*4;
#pragma unroll
      for (int j = 0; j < 4; ++j) {
        float v = acc[i][j] + bb[j];
        v = 0.5f * v * (1.f + erff(v * 0.70710678118654752f));
        hp[j] = f32_to_bf16(v);
      }
    }
  }
}

__global__ __launch_bounds__(256) void moe_ffn2(
    const u16* __restrict__ Hbuf, const float* __restrict__ W2,
    const float* __restrict__ B2, const int* __restrict__ cnt_used,
    const int* __restrict__ row_off, float* __restrict__ Yexp)
{
  const int e = blockIdx.z;
  const int cnt = cnt_used[e];
  const int m0 = blockIdx.x * 64;
  if (m0 >= cnt) return;
  const int n0 = blockIdx.y * 64;
  const int g0 = row_off[e];
  const float* W2e = W2 + (size_t)e * D_FF * D_MODEL;
  __shared__ float As[16][64];
  __shared__ float Bs[16][64];
  const int t  = threadIdx.x;
  const int tx = t & 15, ty = t >> 4;
  const int r  = t >> 2, kq = t & 3;
  const bool rvalid = (m0 + r) < cnt;
  const u16* Hrow = Hbuf + (size_t)(g0 + m0 + r) * D_FF + kq * 4;
  float acc[4][4] = {};
  for (int k0 = 0; k0 < D_FF; k0 += 16) {
    float a0 = 0.f, a1 = 0.f, a2 = 0.f, a3 = 0.f;
    if (rvalid) {
      ushort4 hv = *(const ushort4*)(Hrow + k0);
      a0 = bf16_to_f32(hv.x); a1 = bf16_to_f32(hv.y);
      a2 = bf16_to_f32(hv.z); a3 = bf16_to_f32(hv.w);
    }
    float4 b4 = *(const float4*)&W2e[(size_t)(k0 + ty) * D_MODEL + n0 + tx * 4];
    __syncthreads();
    As[kq*4+0][r] = a0; As[kq*4+1][r] = a1;
    As[kq*4+2][r] = a2; As[kq*4+3][r] = a3;
    *(float4*)&Bs[ty][tx*4] = b4;
    __syncthreads();
#pragma unroll
    for (int k = 0; k < 16; ++k) {
      float4 av = *(const float4*)&As[k][ty*4];
      float4 bv = *(const float4*)&Bs[k][tx*4];
      float aa[4] = {av.x, av.y, av.z, av.w};
      float bb[4] = {bv.x, bv.y, bv.z, bv.w};
#pragma unroll
      for (int i = 0; i < 4; ++i)
#pragma unroll
        for (int j = 0; j < 4; ++j)
          acc[i][j] = fmaf(aa[i], bb[j], acc[i][j]);
    }
  }
  float4 bb4 = *(const float4*)&B2[(size_t)e * D_MODEL + n0 + tx*4];
#pragma unroll
  for (int i = 0; i < 4; ++i) {
    int m = m0 + ty*4 + i;
    if (m < cnt) {
      float4 o = {acc[i][0]+bb4.x, acc[i][1]+bb4.y, acc[i][2]+bb4.z, acc[i][3]+bb4.w};
      *(float4*)&Yexp[(size_t)(g0 + m) * D_MODEL + n0 + tx*4] = o;
    }
  }
}

// ---------------------------------------------------------------------------
// Combine + triple layernorm
// ---------------------------------------------------------------------------
__global__ __launch_bounds__(256) void moe_combine(
    const float* __restrict__ Yexp,
    const int* __restrict__ idx0, const int* __restrict__ idx1,
    const int* __restrict__ slot1, const int* __restrict__ slot2,
    const float* __restrict__ gate1, const float* __restrict__ gate2,
    const int* __restrict__ row_off, float* __restrict__ out)
{
  const int tkn = blockIdx.x;
  const int c = threadIdx.x * 4;
  float4 acc = {0.f, 0.f, 0.f, 0.f};
  int s1 = slot1[tkn];
  if (s1 >= 0) {
    int rr = row_off[idx0[tkn]] + s1;
    float g = gate1[tkn];
    float4 y = *(const float4*)&Yexp[(size_t)rr * D_MODEL + c];
    acc.x += g * y.x; acc.y += g * y.y; acc.z += g * y.z; acc.w += g * y.w;
  }
  int s2 = slot2[tkn];
  if (s2 >= 0) {
    int rr = row_off[idx1[tkn]] + s2;
    float g = gate2[tkn];
    float4 y = *(const float4*)&Yexp[(size_t)rr * D_MODEL + c];
    acc.x += g * y.x; acc.y += g * y.y; acc.z += g * y.z; acc.w += g * y.w;
  }
  *(float4*)&out[(size_t)tkn * D_MODEL + c] = acc;
}

__global__ __launch_bounds__(256) void ln_triple(
    float* __restrict__ out,
    const float* __restrict__ g1, const float* __restrict__ b1,
    const float* __restrict__ g2, const float* __restrict__ b2,
    const float* __restrict__ g3, const float* __restrict__ b3)
{
  const int row = blockIdx.x;
  const int t = threadIdx.x;
  __shared__ float red[12];
  float4 x = *(float4*)&out[(size_t)row * D_MODEL + t * 4];
  const float* gs[3] = {g1, g2, g3};
  const float* bs[3] = {b1, b2, b3};
#pragma unroll
  for (int p = 0; p < 3; ++p) {
    float s = x.x + x.y + x.z + x.w;
    float q = x.x*x.x + x.y*x.y + x.z*x.z + x.w*x.w;
#pragma unroll
    for (int off = 32; off > 0; off >>= 1) {
      s += __shfl_xor(s, off);
      q += __shfl_xor(q, off);
    }
    const int wave = t >> 6, lane = t & 63;
    if (lane == 0) { red[wave*2] = s; red[wave*2+1] = q; }
    __syncthreads();
    if (t == 0) {
      red[8] = red[0] + red[2] + red[4] + red[6];
      red[9] = red[1] + red[3] + red[5] + red[7];
    }
    __syncthreads();
    float mean = red[8] * (1.f / 1024.f);
    float var  = red[9] * (1.f / 1024.f) - mean * mean;
    float rinv = rsqrtf(var + LN_EPS);
    float4 gv = *(const float4*)&gs[p][t*4];
    float4 bv = *(const float4*)&bs[p][t*4];
    x.x = (x.x - mean) * rinv * gv.x + bv.x;
    x.y = (x.y - mean) * rinv * gv.y + bv.y;
    x.z = (x.z - mean) * rinv * gv.z + bv.z;
    x.w = (x.w - mean) * rinv * gv.w + bv.w;
    __syncthreads();
  }
  *(float4*)&out[(size_t)row * D_MODEL + t * 4] = x;
}

extern "C" void kernel_launch(void* const* d_in, const int* in_sizes, int n_in,
                              void* d_out, int out_size, void* d_ws, size_t ws_size,
                              hipStream_t stream) {
  (void)in_sizes; (void)n_in; (void)out_size;
  const float* tgt      = (const float*)d_in[0];
  const float* memory   = (const float*)d_in[1];
  const float* w_qkv_sa = (const float*)d_in[2];
  const float* b_qkv_sa = (const float*)d_in[3];
  const float* w_o_sa   = (const float*)d_in[4];
  const float* b_o_sa   = (const float*)d_in[5];
  const float* w_qkv_ca = (const float*)d_in[6];
  const float* b_qkv_ca = (const float*)d_in[7];
  const float* w_o_ca   = (const float*)d_in[8];
  const float* b_o_ca   = (const float*)d_in[9];
  const float* ln1g = (const float*)d_in[10];
  const float* ln1b = (const float*)d_in[11];
  const float* ln2g = (const float*)d_in[12];
  const float* ln2b = (const float*)d_in[13];
  const float* ln3g = (const float*)d_in[14];
  const float* ln3b = (const float*)d_in[15];
  const float* w_gate = (const float*)d_in[16];
  const float* w1  = (const float*)d_in[17];
  const float* b1e = (const float*)d_in[18];
  const float* w2  = (const float*)d_in[19];
  const float* b2e = (const float*)d_in[20];
  float* out = (float*)d_out;

  // Workspace layout (float offsets):
  //   [0, 12.58M)      B_qkv -> q2+kv2 -> Hbuf(lo)
  //   [12.58M, 16.78M) B_ao            -> Hbuf(hi)   (Hbuf = 8192x4096 bf16)
  //   [16.78M, 20.97M) B_x1 -> Xg (8192x1024 bf16) -> Yexp(lo)
  //   [20.97M, 25.17M) B_x2            -> Yexp(hi)
  //   [25.17M, 25.23M) routing arrays (both paths)
  //   [25.23M, 42.01M) W1T  bf16 [E][DFF][D]   (mfma path only)
  //   [42.01M, 58.79M) W2T  bf16 [E][D][DFF]   (mfma path only)
  float* ws     = (float*)d_ws;
  float* B_qkv  = ws;
  float* B_ao   = ws + 12582912;
  float* B_x1   = ws + 16777216;
  float* B_x2   = ws + 20971520;
  u16*   Hbuf   = (u16*)ws;
  float* Yexp   = B_x1;
  float* q2     = B_qkv;
  float* kv2    = B_qkv + 4194304;
  u16*   Xg     = (u16*)B_x1;
  u16*   W1T    = (u16*)(ws + 25231360);
  u16*   W2T    = (u16*)(ws + 42008576);
  int*   idx0     = (int*)(ws + 25165824);
  int*   idx1     = idx0 + NTOK;
  int*   slot1    = idx1 + NTOK;
  int*   slot2    = slot1 + NTOK;
  int*   list_tok = slot2 + NTOK;
  int*   cnt_used = list_tok + N_EXP * CAP;
  int*   row_off  = cnt_used + N_EXP;
  float* gate1    = (float*)(row_off + N_EXP);
  float* gate2    = gate1 + NTOK;
  float* probsum  = gate2 + NTOK;

  const bool use_mfma = ws_size >= 235143168ull;  // 58,785,792 floats

  hipMemsetAsync(probsum, 0, N_EXP * sizeof(float), stream);

  if (use_mfma) {
    transpose_bf16<<<dim3(128, 32, 8), 256, 0, stream>>>(w1, W1T, D_MODEL, D_FF);
    transpose_bf16<<<dim3(32, 128, 8), 256, 0, stream>>>(w2, W2T, D_FF, D_MODEL);
  }

  // ---- self attention ----
  gemm_nt<<<dim3(64, 48), 256, 0, stream>>>(tgt, w_qkv_sa, b_qkv_sa, B_qkv, 3072, 1024);
  flash_attn<<<dim3(64, 32), 256, 0, stream>>>(B_qkv, 3072, B_qkv + 1024, 3072,
                                               B_qkv + 2048, 3072, B_ao, 1024, 2048);
  gemm_nt<<<dim3(64, 16), 256, 0, stream>>>(B_ao, w_o_sa, b_o_sa, B_x1, 1024, 1024);

  // ---- cross attention ----
  gemm_nt<<<dim3(64, 16), 256, 0, stream>>>(B_x1, w_qkv_ca, b_qkv_ca, q2, 1024, 1024);
  gemm_nt<<<dim3(64, 32), 256, 0, stream>>>(memory, w_qkv_ca + (size_t)1024 * 1024,
                                            b_qkv_ca + 1024, kv2, 2048, 1024);
  flash_attn<<<dim3(64, 32), 256, 0, stream>>>(q2, 1024, kv2, 2048,
                                               kv2 + 1024, 2048, B_ao, 1024, 2048);
  gemm_nt<<<dim3(64, 16), 256, 0, stream>>>(B_ao, w_o_ca, b_o_ca, B_x2, 1024, 1024);

  // ---- MoE ----
  gate_topk<<<NTOK, 64, 0, stream>>>(B_x2, w_gate, idx0, idx1, gate1, gate2, probsum);
  route_scan<<<1, 512, 0, stream>>>(idx0, idx1, slot1, slot2, list_tok, cnt_used,
                                    row_off, probsum, out + (size_t)NTOK * D_MODEL);
  if (use_mfma) {
    moe_gather<<<dim3(CAP, 8), 256, 0, stream>>>(B_x2, list_tok, cnt_used, row_off, Xg);
    ffn1_mfma<<<dim3(16, 32, 8), 256, 0, stream>>>(Xg, W1T, b1e, cnt_used, row_off, Hbuf);
    ffn2_mfma<<<dim3(16, 8, 8), 256, 0, stream>>>(Hbuf, W2T, b2e, cnt_used, row_off, Yexp);
  } else {
    moe_ffn1<<<dim3(32, 64, 8), 256, 0, stream>>>(B_x2, list_tok, w1, b1e,
                                                  cnt_used, row_off, Hbuf);
    moe_ffn2<<<dim3(32, 16, 8), 256, 0, stream>>>(Hbuf, w2, b2e, cnt_used, row_off, Yexp);
  }
  moe_combine<<<NTOK, 256, 0, stream>>>(Yexp, idx0, idx1, slot1, slot2,
                                        gate1, gate2, row_off, out);

  // ---- 3x layernorm ----
  ln_triple<<<NTOK, 256, 0, stream>>>(out, ln1g, ln1b, ln2g, ln2b, ln3g, ln3b);
}

// Round 3
// 2050.835 us; speedup vs baseline: 2.5007x; 1.7879x over previous
//
#include <hip/hip_runtime.h>
#include <math.h>

#define D_MODEL 1024
#define NHEADS  16
#define HEAD_D  64
#define NTOK    4096
#define N_EXP   8
#define D_FF    4096
#define CAP     2048
#define LN_EPS  1e-5f

typedef unsigned short u16;
typedef unsigned int   u32;
typedef unsigned long long u64;

typedef __attribute__((ext_vector_type(8))) short bf16x8;
typedef __attribute__((ext_vector_type(4))) float f32x4;

__device__ __forceinline__ float bf16_to_f32(u16 h) {
  return __uint_as_float(((u32)h) << 16);
}
__device__ __forceinline__ u16 f32_to_bf16(float f) {
  u32 u = __float_as_uint(f);
  u32 r = u + 0x7FFFu + ((u >> 16) & 1u);
  return (u16)(r >> 16);
}
// split x into hi+lo bf16 (x ≈ hi + lo, rel err ~2^-17)
__device__ __forceinline__ void split2(float x, u16& h, u16& l) {
  h = f32_to_bf16(x);
  l = f32_to_bf16(x - bf16_to_f32(h));
}

// async 16B global -> LDS
__device__ __forceinline__ void gld16(const u16* g, u16* l) {
  __builtin_amdgcn_global_load_lds(
      (const __attribute__((address_space(1))) unsigned int*)g,
      (__attribute__((address_space(3))) unsigned int*)l, 16, 0, 0);
}

// ---------------------------------------------------------------------------
// split-pack kernels: fp32 [R][1024] -> bf16 [R][3072]
// A-pattern: [hi | lo | hi]   B-pattern: [hi | hi | lo]
// ---------------------------------------------------------------------------
__global__ __launch_bounds__(256) void split_a(
    const float* __restrict__ X, u16* __restrict__ Xp)
{
  const int row = blockIdx.x;
  const int c = threadIdx.x * 4;
  float4 v = *(const float4*)&X[(size_t)row * 1024 + c];
  ushort4 h, l;
  split2(v.x, h.x, l.x); split2(v.y, h.y, l.y);
  split2(v.z, h.z, l.z); split2(v.w, h.w, l.w);
  u16* o = Xp + (size_t)row * 3072;
  *(ushort4*)&o[c] = h;
  *(ushort4*)&o[1024 + c] = l;
  *(ushort4*)&o[2048 + c] = h;
}

__global__ __launch_bounds__(256) void split_b(
    const float* __restrict__ X, u16* __restrict__ Xp)
{
  const int row = blockIdx.x;
  const int c = threadIdx.x * 4;
  float4 v = *(const float4*)&X[(size_t)row * 1024 + c];
  ushort4 h, l;
  split2(v.x, h.x, l.x); split2(v.y, h.y, l.y);
  split2(v.z, h.z, l.z); split2(v.w, h.w, l.w);
  u16* o = Xp + (size_t)row * 3072;
  *(ushort4*)&o[c] = h;
  *(ushort4*)&o[1024 + c] = h;
  *(ushort4*)&o[2048 + c] = l;
}

// ---------------------------------------------------------------------------
// split-bf16 GEMM (NT): Y[m,n] = sum_k A[m,k]*W[n,k] + bias[n], fp32-class acc.
// A' [M][3072], B' [N][3072] pre-split-packed. 128x128 tile, BK=64.
// grid (M/128, N/128), 256 thr.
// ---------------------------------------------------------------------------
__global__ __launch_bounds__(256) void gemm_x3(
    const u16* __restrict__ Ax, const u16* __restrict__ Bx,
    const float* __restrict__ bias, float* __restrict__ Y, int ldy)
{
  const int m0 = blockIdx.x * 128, n0 = blockIdx.y * 128;
  __shared__ __align__(16) u16 As[128 * 64];
  __shared__ __align__(16) u16 Bs[128 * 64];
  const int t = threadIdx.x;
  const int lane = t & 63;
  const int wm = ((t >> 6) & 1) * 64;
  const int wn = ((t >> 6) >> 1) * 64;
  const u16* Ab = Ax + (size_t)m0 * 3072;
  const u16* Bb = Bx + (size_t)n0 * 3072;
  f32x4 acc[4][4] = {};
  int srow[4], scol[4];
#pragma unroll
  for (int i = 0; i < 4; ++i) {
    int id = t + i * 256;
    srow[i] = id >> 3;
    scol[i] = (id & 7) ^ (srow[i] & 7);
  }
  for (int k0 = 0; k0 < 3072; k0 += 64) {
    __syncthreads();
#pragma unroll
    for (int i = 0; i < 4; ++i) {
      gld16(Ab + (size_t)srow[i] * 3072 + k0 + scol[i] * 8, &As[(t + i*256) * 8]);
      gld16(Bb + (size_t)srow[i] * 3072 + k0 + scol[i] * 8, &Bs[(t + i*256) * 8]);
    }
    __syncthreads();
#pragma unroll
    for (int ks = 0; ks < 2; ++ks) {
      bf16x8 af[4], bfr[4];
      const int q = ks * 4 + (lane >> 4);
#pragma unroll
      for (int i = 0; i < 4; ++i) {
        int m = wm + i * 16 + (lane & 15);
        af[i]  = *(const bf16x8*)&As[m * 64 + ((q ^ (m & 7)) * 8)];
        int n = wn + i * 16 + (lane & 15);
        bfr[i] = *(const bf16x8*)&Bs[n * 64 + ((q ^ (n & 7)) * 8)];
      }
#pragma unroll
      for (int mi = 0; mi < 4; ++mi)
#pragma unroll
        for (int ni = 0; ni < 4; ++ni)
          acc[mi][ni] = __builtin_amdgcn_mfma_f32_16x16x32_bf16(
              af[mi], bfr[ni], acc[mi][ni], 0, 0, 0);
    }
  }
  const int ncol = n0 + wn + (lane & 15);
  float bias_n[4];
#pragma unroll
  for (int ni = 0; ni < 4; ++ni)
    bias_n[ni] = bias[ncol + ni * 16];
  const int rbase = m0 + wm + (lane >> 4) * 4;
#pragma unroll
  for (int mi = 0; mi < 4; ++mi)
#pragma unroll
    for (int rg = 0; rg < 4; ++rg) {
      int m = rbase + mi * 16 + rg;
      float* yp = Y + (size_t)m * ldy + ncol;
#pragma unroll
      for (int ni = 0; ni < 4; ++ni)
        yp[ni * 16] = acc[mi][ni][rg] + bias_n[ni];
    }
}

// ---------------------------------------------------------------------------
// Split-bf16 MFMA flash attention.
// grid (Sq/256, B*NHEADS), 256 thr = 4 waves; wave owns 64 q-rows.
// K/V tiles of 64 staged hi/lo in LDS; P round-trips LDS per 32-sk half.
// token t = s*2 + b.
// ---------------------------------------------------------------------------
__global__ __launch_bounds__(256, 2) void flash_mfma(
    const float* __restrict__ Q, int ldq,
    const float* __restrict__ Kg, int ldk,
    const float* __restrict__ Vg, int ldv,
    float* __restrict__ O, int ldo)
{
  const int qt = blockIdx.x;
  const int bh = blockIdx.y;
  const int b  = bh >> 4;
  const int col = (bh & 15) * HEAD_D;
  __shared__ u16 Ks[64][136];      // [sk][d-hi 64 | d-lo 64 | pad]
  __shared__ u16 Vs[64][136];      // [d][sk-hi 64 | sk-lo 64 | pad]
  __shared__ u16 Ps[4][64][72];    // per-wave [q][sk-hi 32 | sk-lo 32 | pad]
  const int t = threadIdx.x, w = t >> 6, lane = t & 63;
  const int quad = lane >> 4, l15 = lane & 15;
  const int q0 = qt * 256 + w * 64;

  // Q fragments (A-layout: m=l15, k=quad*8+j), hi/lo
  bf16x8 Qf[4][2][2];
#pragma unroll
  for (int mi = 0; mi < 4; ++mi)
#pragma unroll
    for (int kc = 0; kc < 2; ++kc) {
      const float* qp = &Q[(size_t)((q0 + mi*16 + l15) * 2 + b) * ldq
                           + col + kc * 32 + quad * 8];
      float4 a = *(const float4*)qp;
      float4 c = *(const float4*)(qp + 4);
      float v[8] = {a.x, a.y, a.z, a.w, c.x, c.y, c.z, c.w};
      bf16x8 hf, lf;
#pragma unroll
      for (int j = 0; j < 8; ++j) {
        u16 h, l; split2(v[j], h, l);
        hf[j] = (short)h; lf[j] = (short)l;
      }
      Qf[mi][kc][0] = hf; Qf[mi][kc][1] = lf;
    }

  float mst[4][4], lst[4][4];
#pragma unroll
  for (int mi = 0; mi < 4; ++mi)
#pragma unroll
    for (int r = 0; r < 4; ++r) { mst[mi][r] = -3.0e38f; lst[mi][r] = 0.f; }
  f32x4 Oa[4][4] = {};

  for (int kt = 0; kt < 32; ++kt) {
    __syncthreads();
    // stage K (hi/lo) and V (transposed, hi/lo)
#pragma unroll
    for (int i = 0; i < 4; ++i) {
      int r = lane, c0 = w * 16 + i * 4;
      float4 kv = *(const float4*)&Kg[(size_t)((kt*64 + r)*2 + b) * ldk + col + c0];
      ushort4 h4, l4;
      split2(kv.x, h4.x, l4.x); split2(kv.y, h4.y, l4.y);
      split2(kv.z, h4.z, l4.z); split2(kv.w, h4.w, l4.w);
      *(ushort4*)&Ks[r][c0]      = h4;
      *(ushort4*)&Ks[r][64 + c0] = l4;
      float4 vv = *(const float4*)&Vg[(size_t)((kt*64 + r)*2 + b) * ldv + col + c0];
      float va[4] = {vv.x, vv.y, vv.z, vv.w};
#pragma unroll
      for (int j = 0; j < 4; ++j) {
        u16 h, l; split2(va[j], h, l);
        Vs[c0 + j][r]      = h;
        Vs[c0 + j][64 + r] = l;
      }
    }
    __syncthreads();
    // S = Q K^T (3-term split)
    f32x4 S[4][4] = {};
#pragma unroll
    for (int kc = 0; kc < 2; ++kc)
#pragma unroll
      for (int ns = 0; ns < 4; ++ns) {
        bf16x8 kh = *(const bf16x8*)&Ks[ns*16 + l15][kc*32 + quad*8];
        bf16x8 kl = *(const bf16x8*)&Ks[ns*16 + l15][64 + kc*32 + quad*8];
#pragma unroll
        for (int mi = 0; mi < 4; ++mi) {
          S[mi][ns] = __builtin_amdgcn_mfma_f32_16x16x32_bf16(Qf[mi][kc][0], kh, S[mi][ns], 0,0,0);
          S[mi][ns] = __builtin_amdgcn_mfma_f32_16x16x32_bf16(Qf[mi][kc][1], kh, S[mi][ns], 0,0,0);
          S[mi][ns] = __builtin_amdgcn_mfma_f32_16x16x32_bf16(Qf[mi][kc][0], kl, S[mi][ns], 0,0,0);
        }
      }
    // online softmax (rows: q = mi*16 + quad*4 + r; cols across l15 and ns)
#pragma unroll
    for (int mi = 0; mi < 4; ++mi) {
#pragma unroll
      for (int ns = 0; ns < 4; ++ns)
#pragma unroll
        for (int r = 0; r < 4; ++r)
          S[mi][ns][r] *= 0.125f;
      float mx[4], al[4], ls[4];
#pragma unroll
      for (int r = 0; r < 4; ++r)
        mx[r] = fmaxf(fmaxf(S[mi][0][r], S[mi][1][r]),
                      fmaxf(S[mi][2][r], S[mi][3][r]));
#pragma unroll
      for (int off = 1; off < 16; off <<= 1)
#pragma unroll
        for (int r = 0; r < 4; ++r)
          mx[r] = fmaxf(mx[r], __shfl_xor(mx[r], off));
#pragma unroll
      for (int r = 0; r < 4; ++r) {
        float mnew = fmaxf(mst[mi][r], mx[r]);
        al[r] = __expf(mst[mi][r] - mnew);
        mst[mi][r] = mnew;
        ls[r] = 0.f;
      }
#pragma unroll
      for (int ns = 0; ns < 4; ++ns)
#pragma unroll
        for (int r = 0; r < 4; ++r) {
          float p = __expf(S[mi][ns][r] - mst[mi][r]);
          S[mi][ns][r] = p;
          ls[r] += p;
        }
#pragma unroll
      for (int off = 1; off < 16; off <<= 1)
#pragma unroll
        for (int r = 0; r < 4; ++r)
          ls[r] += __shfl_xor(ls[r], off);
#pragma unroll
      for (int r = 0; r < 4; ++r)
        lst[mi][r] = lst[mi][r] * al[r] + ls[r];
#pragma unroll
      for (int ns = 0; ns < 4; ++ns)
#pragma unroll
        for (int r = 0; r < 4; ++r)
          Oa[mi][ns][r] *= al[r];
    }
    // O += P V  in two 32-sk halves (P via per-wave LDS, hi/lo split)
#pragma unroll
    for (int kc = 0; kc < 2; ++kc) {
#pragma unroll
      for (int mi = 0; mi < 4; ++mi)
#pragma unroll
        for (int nn = 0; nn < 2; ++nn) {
          int ns = kc * 2 + nn;
          int skc = nn * 16 + l15;
#pragma unroll
          for (int r = 0; r < 4; ++r) {
            float p = S[mi][ns][r];
            u16 h, l; split2(p, h, l);
            int q = mi * 16 + quad * 4 + r;
            Ps[w][q][skc]      = h;
            Ps[w][q][32 + skc] = l;
          }
        }
      bf16x8 ph[4], pl[4];
#pragma unroll
      for (int mi = 0; mi < 4; ++mi) {
        ph[mi] = *(const bf16x8*)&Ps[w][mi*16 + l15][quad * 8];
        pl[mi] = *(const bf16x8*)&Ps[w][mi*16 + l15][32 + quad * 8];
      }
#pragma unroll
      for (int ns2 = 0; ns2 < 4; ++ns2) {
        bf16x8 vh = *(const bf16x8*)&Vs[ns2*16 + l15][kc*32 + quad*8];
        bf16x8 vl = *(const bf16x8*)&Vs[ns2*16 + l15][64 + kc*32 + quad*8];
#pragma unroll
        for (int mi = 0; mi < 4; ++mi) {
          Oa[mi][ns2] = __builtin_amdgcn_mfma_f32_16x16x32_bf16(ph[mi], vh, Oa[mi][ns2], 0,0,0);
          Oa[mi][ns2] = __builtin_amdgcn_mfma_f32_16x16x32_bf16(pl[mi], vh, Oa[mi][ns2], 0,0,0);
          Oa[mi][ns2] = __builtin_amdgcn_mfma_f32_16x16x32_bf16(ph[mi], vl, Oa[mi][ns2], 0,0,0);
        }
      }
    }
  }
  // epilogue
#pragma unroll
  for (int mi = 0; mi < 4; ++mi) {
    float rl[4];
#pragma unroll
    for (int r = 0; r < 4; ++r) rl[r] = 1.f / lst[mi][r];
#pragma unroll
    for (int ns = 0; ns < 4; ++ns)
#pragma unroll
      for (int r = 0; r < 4; ++r)
        O[(size_t)((q0 + mi*16 + quad*4 + r) * 2 + b) * ldo + col + ns*16 + l15]
            = Oa[mi][ns][r] * rl[r];
  }
}

// ---------------------------------------------------------------------------
// fp32 GEMM (NT) — fallback path only
// ---------------------------------------------------------------------------
__global__ __launch_bounds__(256) void gemm_nt(
    const float* __restrict__ A, const float* __restrict__ W,
    const float* __restrict__ bias, float* __restrict__ Y,
    int ldy, int K)
{
  const int m0 = blockIdx.x * 64;
  const int n0 = blockIdx.y * 64;
  __shared__ float As[16][64];
  __shared__ float Bs[16][64];
  const int t  = threadIdx.x;
  const int tx = t & 15, ty = t >> 4;
  const int r  = t >> 2, kq = t & 3;
  const float* Ap = A + (size_t)(m0 + r) * K + kq * 4;
  const float* Wp = W + (size_t)(n0 + r) * K + kq * 4;
  float acc[4][4] = {};
  for (int k0 = 0; k0 < K; k0 += 16) {
    float4 a4 = *(const float4*)(Ap + k0);
    float4 b4 = *(const float4*)(Wp + k0);
    __syncthreads();
    As[kq*4+0][r] = a4.x; As[kq*4+1][r] = a4.y;
    As[kq*4+2][r] = a4.z; As[kq*4+3][r] = a4.w;
    Bs[kq*4+0][r] = b4.x; Bs[kq*4+1][r] = b4.y;
    Bs[kq*4+2][r] = b4.z; Bs[kq*4+3][r] = b4.w;
    __syncthreads();
#pragma unroll
    for (int k = 0; k < 16; ++k) {
      float4 av = *(const float4*)&As[k][ty*4];
      float4 bv = *(const float4*)&Bs[k][tx*4];
      float aa[4] = {av.x, av.y, av.z, av.w};
      float bb[4] = {bv.x, bv.y, bv.z, bv.w};
#pragma unroll
      for (int i = 0; i < 4; ++i)
#pragma unroll
        for (int j = 0; j < 4; ++j)
          acc[i][j] = fmaf(aa[i], bb[j], acc[i][j]);
    }
  }
  float4 bv4 = *(const float4*)&bias[n0 + tx*4];
  float bb[4] = {bv4.x, bv4.y, bv4.z, bv4.w};
#pragma unroll
  for (int i = 0; i < 4; ++i) {
    float4 o;
    o.x = acc[i][0] + bb[0]; o.y = acc[i][1] + bb[1];
    o.z = acc[i][2] + bb[2]; o.w = acc[i][3] + bb[3];
    *(float4*)&Y[(size_t)(m0 + ty*4 + i) * ldy + n0 + tx*4] = o;
  }
}

// ---------------------------------------------------------------------------
// fp32 flash attention — fallback path only
// ---------------------------------------------------------------------------
__global__ __launch_bounds__(256) void flash_attn(
    const float* __restrict__ Q, int ldq,
    const float* __restrict__ Kp, int ldk,
    const float* __restrict__ Vp, int ldv,
    float* __restrict__ O, int ldo, int Sk)
{
  const int qt = blockIdx.x;
  const int bh = blockIdx.y;
  const int b  = bh >> 4;
  const int h  = bh & 15;
  const int col = h * HEAD_D;
  __shared__ float Qs[64][36];
  __shared__ float Ks2[64][68];
  __shared__ float Vs2[64][68];
  __shared__ float Ss[64][36];
  __shared__ float m_s[32], l_s[32], al_s[32];
  const int t  = threadIdx.x;
  const int tx = t & 15, ty = t >> 4;
#pragma unroll
  for (int p = 0; p < 2; ++p) {
    int id = t + p * 256;
    int r = id >> 4, dq = id & 15;
    int s = qt * 32 + r;
    float4 q4 = *(const float4*)&Q[(size_t)(s * 2 + b) * ldq + col + dq * 4];
    Qs[dq*4+0][r] = q4.x; Qs[dq*4+1][r] = q4.y;
    Qs[dq*4+2][r] = q4.z; Qs[dq*4+3][r] = q4.w;
  }
  if (t < 32) { m_s[t] = -1e30f; l_s[t] = 0.f; }
  float o[2][4] = {};
  for (int kt = 0; kt < Sk / 64; ++kt) {
    __syncthreads();
#pragma unroll
    for (int p = 0; p < 4; ++p) {
      int id = t + p * 256;
      int r = id >> 4, dq = id & 15;
      int sk = kt * 64 + r;
      float4 k4 = *(const float4*)&Kp[(size_t)(sk * 2 + b) * ldk + col + dq * 4];
      Ks2[dq*4+0][r] = k4.x; Ks2[dq*4+1][r] = k4.y;
      Ks2[dq*4+2][r] = k4.z; Ks2[dq*4+3][r] = k4.w;
      float4 v4 = *(const float4*)&Vp[(size_t)(sk * 2 + b) * ldv + col + dq * 4];
      *(float4*)&Vs2[r][dq*4] = v4;
    }
    __syncthreads();
    float sc[2][4] = {};
#pragma unroll
    for (int d = 0; d < 64; ++d) {
      float2 a2 = *(const float2*)&Qs[d][ty*2];
      float4 b4 = *(const float4*)&Ks2[d][tx*4];
      sc[0][0] = fmaf(a2.x, b4.x, sc[0][0]);
      sc[0][1] = fmaf(a2.x, b4.y, sc[0][1]);
      sc[0][2] = fmaf(a2.x, b4.z, sc[0][2]);
      sc[0][3] = fmaf(a2.x, b4.w, sc[0][3]);
      sc[1][0] = fmaf(a2.y, b4.x, sc[1][0]);
      sc[1][1] = fmaf(a2.y, b4.y, sc[1][1]);
      sc[1][2] = fmaf(a2.y, b4.z, sc[1][2]);
      sc[1][3] = fmaf(a2.y, b4.w, sc[1][3]);
    }
#pragma unroll
    for (int j = 0; j < 4; ++j) {
      Ss[tx*4+j][ty*2+0] = sc[0][j] * 0.125f;
      Ss[tx*4+j][ty*2+1] = sc[1][j] * 0.125f;
    }
    __syncthreads();
    {
      int row = t >> 3, oct = t & 7;
      float mx = -1e30f;
#pragma unroll
      for (int jj = 0; jj < 8; ++jj)
        mx = fmaxf(mx, Ss[oct*8+jj][row]);
      mx = fmaxf(mx, __shfl_xor(mx, 1));
      mx = fmaxf(mx, __shfl_xor(mx, 2));
      mx = fmaxf(mx, __shfl_xor(mx, 4));
      float m_old = m_s[row];
      float m_new = fmaxf(m_old, mx);
      float sum = 0.f;
#pragma unroll
      for (int jj = 0; jj < 8; ++jj) {
        float p = __expf(Ss[oct*8+jj][row] - m_new);
        Ss[oct*8+jj][row] = p;
        sum += p;
      }
      sum += __shfl_xor(sum, 1);
      sum += __shfl_xor(sum, 2);
      sum += __shfl_xor(sum, 4);
      if (oct == 0) {
        float al = __expf(m_old - m_new);
        al_s[row] = al;
        l_s[row]  = l_s[row] * al + sum;
        m_s[row]  = m_new;
      }
    }
    __syncthreads();
    float al0 = al_s[ty*2+0], al1 = al_s[ty*2+1];
#pragma unroll
    for (int j = 0; j < 4; ++j) { o[0][j] *= al0; o[1][j] *= al1; }
#pragma unroll
    for (int jj = 0; jj < 64; ++jj) {
      float2 p2 = *(const float2*)&Ss[jj][ty*2];
      float4 v4 = *(const float4*)&Vs2[jj][tx*4];
      o[0][0] = fmaf(p2.x, v4.x, o[0][0]);
      o[0][1] = fmaf(p2.x, v4.y, o[0][1]);
      o[0][2] = fmaf(p2.x, v4.z, o[0][2]);
      o[0][3] = fmaf(p2.x, v4.w, o[0][3]);
      o[1][0] = fmaf(p2.y, v4.x, o[1][0]);
      o[1][1] = fmaf(p2.y, v4.y, o[1][1]);
      o[1][2] = fmaf(p2.y, v4.z, o[1][2]);
      o[1][3] = fmaf(p2.y, v4.w, o[1][3]);
    }
  }
  float li0 = 1.f / l_s[ty*2+0];
  float li1 = 1.f / l_s[ty*2+1];
  int s0 = qt * 32 + ty * 2;
  float4 o0 = {o[0][0]*li0, o[0][1]*li0, o[0][2]*li0, o[0][3]*li0};
  *(float4*)&O[(size_t)(s0 * 2 + b) * ldo + col + tx*4] = o0;
  float4 o1 = {o[1][0]*li1, o[1][1]*li1, o[1][2]*li1, o[1][3]*li1};
  *(float4*)&O[(size_t)((s0 + 1) * 2 + b) * ldo + col + tx*4] = o1;
}

// ---------------------------------------------------------------------------
// Gate: logits = x @ w_gate (1024x8), softmax, top-2. One wave per token. fp32.
// ---------------------------------------------------------------------------
__global__ __launch_bounds__(64) void gate_topk(
    const float* __restrict__ X, const float* __restrict__ Wg,
    int* __restrict__ idx0, int* __restrict__ idx1,
    float* __restrict__ gate1, float* __restrict__ gate2,
    float* __restrict__ probsum)
{
  const int tkn = blockIdx.x;
  const int lane = threadIdx.x;
  float acc[8] = {};
  for (int k = lane; k < D_MODEL; k += 64) {
    float xv = X[(size_t)tkn * D_MODEL + k];
    const float4* w4 = (const float4*)&Wg[k * 8];
    float4 wa = w4[0], wb = w4[1];
    acc[0] = fmaf(xv, wa.x, acc[0]); acc[1] = fmaf(xv, wa.y, acc[1]);
    acc[2] = fmaf(xv, wa.z, acc[2]); acc[3] = fmaf(xv, wa.w, acc[3]);
    acc[4] = fmaf(xv, wb.x, acc[4]); acc[5] = fmaf(xv, wb.y, acc[5]);
    acc[6] = fmaf(xv, wb.z, acc[6]); acc[7] = fmaf(xv, wb.w, acc[7]);
  }
#pragma unroll
  for (int off = 32; off > 0; off >>= 1)
#pragma unroll
    for (int e = 0; e < 8; ++e)
      acc[e] += __shfl_xor(acc[e], off);
  if (lane == 0) {
    float mx = acc[0];
#pragma unroll
    for (int e = 1; e < 8; ++e) mx = fmaxf(mx, acc[e]);
    float p[8], s = 0.f;
#pragma unroll
    for (int e = 0; e < 8; ++e) { p[e] = __expf(acc[e] - mx); s += p[e]; }
    float inv = 1.f / s;
#pragma unroll
    for (int e = 0; e < 8; ++e) p[e] *= inv;
    int e0 = 0; float p0 = p[0];
#pragma unroll
    for (int e = 1; e < 8; ++e) if (p[e] > p0) { p0 = p[e]; e0 = e; }
    int e1 = (e0 == 0) ? 1 : 0; float p1 = p[e1];
#pragma unroll
    for (int e = 0; e < 8; ++e) if (e != e0 && p[e] > p1) { p1 = p[e]; e1 = e; }
    idx0[tkn] = e0; idx1[tkn] = e1;
    gate1[tkn] = p0; gate2[tkn] = p1;
#pragma unroll
    for (int e = 0; e < 8; ++e) atomicAdd(&probsum[e], p[e]);
  }
}

// ---------------------------------------------------------------------------
// Routing scan: faithful cumsum/capacity semantics. 1 block, 8 waves.
// ---------------------------------------------------------------------------
__global__ __launch_bounds__(512) void route_scan(
    const int* __restrict__ idx0, const int* __restrict__ idx1,
    int* __restrict__ slot1, int* __restrict__ slot2,
    int* __restrict__ list_tok, int* __restrict__ cnt_used,
    int* __restrict__ row_off, const float* __restrict__ probsum,
    float* __restrict__ aux_out)
{
  __shared__ int sh_used[8];
  __shared__ int sh_cnt1[8];
  const int e = threadIdx.x >> 6;
  const int lane = threadIdx.x & 63;
  const u64 ltmask = (1ull << lane) - 1ull;
  int run = 0;
  for (int c = 0; c < NTOK / 64; ++c) {
    int tk = c * 64 + lane;
    bool f = (idx0[tk] == e);
    u64 m = __ballot(f);
    if (f) {
      int loc = run + __popcll(m & ltmask);
      slot1[tk] = (loc < CAP) ? loc : -1;
      if (loc < CAP) list_tok[e * CAP + loc] = tk;
    }
    run += __popcll(m);
  }
  const int count1 = run;
  int run2 = 0;
  for (int c = 0; c < NTOK / 64; ++c) {
    int tk = c * 64 + lane;
    bool f = (idx1[tk] == e);
    u64 m = __ballot(f);
    if (f) {
      int loc = count1 + run2 + __popcll(m & ltmask);
      slot2[tk] = (loc < CAP) ? loc : -1;
      if (loc < CAP) list_tok[e * CAP + loc] = tk;
    }
    run2 += __popcll(m);
  }
  if (lane == 0) {
    int used = count1 + run2; if (used > CAP) used = CAP;
    sh_used[e] = used;
    sh_cnt1[e] = count1;
  }
  __syncthreads();
  if (threadIdx.x == 0) {
    int off = 0;
    float aux = 0.f;
    for (int k = 0; k < 8; ++k) {
      row_off[k]  = off;
      cnt_used[k] = sh_used[k];
      off += sh_used[k];
      aux += ((float)sh_cnt1[k] / (float)NTOK) * (probsum[k] / (float)NTOK);
    }
    aux_out[0] = 0.01f * 8.f * aux;
  }
}

// ---------------------------------------------------------------------------
// Transpose + fp32->bf16: in [R][C] -> out [C][R]  (per blockIdx.z matrix)
// ---------------------------------------------------------------------------
__global__ __launch_bounds__(256) void transpose_bf16(
    const float* __restrict__ in, u16* __restrict__ outp, int R, int C)
{
  __shared__ u16 tile[32][33];
  const size_t mat = (size_t)blockIdx.z * R * C;
  const int c0 = blockIdx.x * 32, r0 = blockIdx.y * 32;
  const int t = threadIdx.x;
  {
    int r = t >> 3, cq = (t & 7) * 4;
    float4 v = *(const float4*)&in[mat + (size_t)(r0 + r) * C + c0 + cq];
    tile[r][cq+0] = f32_to_bf16(v.x);
    tile[r][cq+1] = f32_to_bf16(v.y);
    tile[r][cq+2] = f32_to_bf16(v.z);
    tile[r][cq+3] = f32_to_bf16(v.w);
  }
  __syncthreads();
  {
    int c = t >> 3, rq = (t & 7) * 4;
    ushort4 ov;
    ov.x = tile[rq+0][c]; ov.y = tile[rq+1][c];
    ov.z = tile[rq+2][c]; ov.w = tile[rq+3][c];
    *(ushort4*)&outp[mat + (size_t)(c0 + c) * R + r0 + rq] = ov;
  }
}

// ---------------------------------------------------------------------------
// Gather routed tokens -> packed bf16 rows Xg[g0+m][1024]
// ---------------------------------------------------------------------------
__global__ __launch_bounds__(256) void moe_gather(
    const float* __restrict__ X, const int* __restrict__ list_tok,
    const int* __restrict__ cnt_used, const int* __restrict__ row_off,
    u16* __restrict__ Xg)
{
  const int e = blockIdx.y;
  const int m = blockIdx.x;
  if (m >= cnt_used[e]) return;
  const int tok = list_tok[e * CAP + m];
  const int g = row_off[e] + m;
  const int c = threadIdx.x * 4;
  float4 v = *(const float4*)&X[(size_t)tok * D_MODEL + c];
  ushort4 o;
  o.x = f32_to_bf16(v.x); o.y = f32_to_bf16(v.y);
  o.z = f32_to_bf16(v.z); o.w = f32_to_bf16(v.w);
  *(ushort4*)&Xg[(size_t)g * D_MODEL + c] = o;
}

// ---------------------------------------------------------------------------
// MFMA FFN1: H = gelu(Xg @ W1T^T + b1) -> bf16. 128x128 tile, BK=64.
// ---------------------------------------------------------------------------
__global__ __launch_bounds__(256) void ffn1_mfma(
    const u16* __restrict__ Xg, const u16* __restrict__ W1T,
    const float* __restrict__ B1,
    const int* __restrict__ cnt_used, const int* __restrict__ row_off,
    u16* __restrict__ Hbuf)
{
  const int e = blockIdx.z;
  const int cnt = cnt_used[e];
  const int m0 = blockIdx.x * 128;
  if (m0 >= cnt) return;
  const int n0 = blockIdx.y * 128;
  const int g0 = row_off[e];
  __shared__ __align__(16) u16 As[128 * 64];
  __shared__ __align__(16) u16 Bs[128 * 64];
  const int t = threadIdx.x;
  const int lane = t & 63;
  const int wm = ((t >> 6) & 1) * 64;
  const int wn = ((t >> 6) >> 1) * 64;
  const u16* Ab = Xg + (size_t)(g0 + m0) * D_MODEL;
  const u16* Bb = W1T + (size_t)e * ((size_t)D_FF * D_MODEL) + (size_t)n0 * D_MODEL;
  f32x4 acc[4][4] = {};
  int srow[4], scol[4];
#pragma unroll
  for (int i = 0; i < 4; ++i) {
    int id = t + i * 256;
    srow[i] = id >> 3;
    scol[i] = (id & 7) ^ (srow[i] & 7);
  }
  for (int k0 = 0; k0 < D_MODEL; k0 += 64) {
    __syncthreads();
#pragma unroll
    for (int i = 0; i < 4; ++i) {
      int r  = srow[i];
      int ra = (m0 + r < cnt) ? r : 0;
      gld16(Ab + (size_t)ra * D_MODEL + k0 + scol[i] * 8, &As[(t + i*256) * 8]);
      gld16(Bb + (size_t)r  * D_MODEL + k0 + scol[i] * 8, &Bs[(t + i*256) * 8]);
    }
    __syncthreads();
#pragma unroll
    for (int ks = 0; ks < 2; ++ks) {
      bf16x8 af[4], bfr[4];
      const int q = ks * 4 + (lane >> 4);
#pragma unroll
      for (int i = 0; i < 4; ++i) {
        int m = wm + i * 16 + (lane & 15);
        af[i]  = *(const bf16x8*)&As[m * 64 + ((q ^ (m & 7)) * 8)];
        int n = wn + i * 16 + (lane & 15);
        bfr[i] = *(const bf16x8*)&Bs[n * 64 + ((q ^ (n & 7)) * 8)];
      }
#pragma unroll
      for (int mi = 0; mi < 4; ++mi)
#pragma unroll
        for (int ni = 0; ni < 4; ++ni)
          acc[mi][ni] = __builtin_amdgcn_mfma_f32_16x16x32_bf16(
              af[mi], bfr[ni], acc[mi][ni], 0, 0, 0);
    }
  }
  float bias_n[4];
  const int ncol = n0 + wn + (lane & 15);
#pragma unroll
  for (int ni = 0; ni < 4; ++ni)
    bias_n[ni] = B1[e * D_FF + ncol + ni * 16];
  const int rbase = m0 + wm + (lane >> 4) * 4;
#pragma unroll
  for (int mi = 0; mi < 4; ++mi) {
#pragma unroll
    for (int rg = 0; rg < 4; ++rg) {
      int m = rbase + mi * 16 + rg;
      if (m < cnt) {
        u16* hp = Hbuf + (size_t)(g0 + m) * D_FF + ncol;
#pragma unroll
        for (int ni = 0; ni < 4; ++ni) {
          float v = acc[mi][ni][rg] + bias_n[ni];
          v = 0.5f * v * (1.f + erff(v * 0.70710678118654752f));
          hp[ni * 16] = f32_to_bf16(v);
        }
      }
    }
  }
}

// ---------------------------------------------------------------------------
// MFMA FFN2: Yexp = Hbuf @ W2T^T + b2 (fp32 out).
// ---------------------------------------------------------------------------
__global__ __launch_bounds__(256) void ffn2_mfma(
    const u16* __restrict__ Hbuf, const u16* __restrict__ W2T,
    const float* __restrict__ B2,
    const int* __restrict__ cnt_used, const int* __restrict__ row_off,
    float* __restrict__ Yexp)
{
  const int e = blockIdx.z;
  const int cnt = cnt_used[e];
  const int m0 = blockIdx.x * 128;
  if (m0 >= cnt) return;
  const int n0 = blockIdx.y * 128;
  const int g0 = row_off[e];
  __shared__ __align__(16) u16 As[128 * 64];
  __shared__ __align__(16) u16 Bs[128 * 64];
  const int t = threadIdx.x;
  const int lane = t & 63;
  const int wm = ((t >> 6) & 1) * 64;
  const int wn = ((t >> 6) >> 1) * 64;
  const u16* Ab = Hbuf + (size_t)(g0 + m0) * D_FF;
  const u16* Bb = W2T + (size_t)e * ((size_t)D_MODEL * D_FF) + (size_t)n0 * D_FF;
  f32x4 acc[4][4] = {};
  int srow[4], scol[4];
#pragma unroll
  for (int i = 0; i < 4; ++i) {
    int id = t + i * 256;
    srow[i] = id >> 3;
    scol[i] = (id & 7) ^ (srow[i] & 7);
  }
  for (int k0 = 0; k0 < D_FF; k0 += 64) {
    __syncthreads();
#pragma unroll
    for (int i = 0; i < 4; ++i) {
      int r  = srow[i];
      int ra = (m0 + r < cnt) ? r : 0;
      gld16(Ab + (size_t)ra * D_FF + k0 + scol[i] * 8, &As[(t + i*256) * 8]);
      gld16(Bb + (size_t)r  * D_FF + k0 + scol[i] * 8, &Bs[(t + i*256) * 8]);
    }
    __syncthreads();
#pragma unroll
    for (int ks = 0; ks < 2; ++ks) {
      bf16x8 af[4], bfr[4];
      const int q = ks * 4 + (lane >> 4);
#pragma unroll
      for (int i = 0; i < 4; ++i) {
        int m = wm + i * 16 + (lane & 15);
        af[i]  = *(const bf16x8*)&As[m * 64 + ((q ^ (m & 7)) * 8)];
        int n = wn + i * 16 + (lane & 15);
        bfr[i] = *(const bf16x8*)&Bs[n * 64 + ((q ^ (n & 7)) * 8)];
      }
#pragma unroll
      for (int mi = 0; mi < 4; ++mi)
#pragma unroll
        for (int ni = 0; ni < 4; ++ni)
          acc[mi][ni] = __builtin_amdgcn_mfma_f32_16x16x32_bf16(
              af[mi], bfr[ni], acc[mi][ni], 0, 0, 0);
    }
  }
  float bias_n[4];
  const int ncol = n0 + wn + (lane & 15);
#pragma unroll
  for (int ni = 0; ni < 4; ++ni)
    bias_n[ni] = B2[e * D_MODEL + ncol + ni * 16];
  const int rbase = m0 + wm + (lane >> 4) * 4;
#pragma unroll
  for (int mi = 0; mi < 4; ++mi) {
#pragma unroll
    for (int rg = 0; rg < 4; ++rg) {
      int m = rbase + mi * 16 + rg;
      if (m < cnt) {
        float* yp = Yexp + (size_t)(g0 + m) * D_MODEL + ncol;
#pragma unroll
        for (int ni = 0; ni < 4; ++ni)
          yp[ni * 16] = acc[mi][ni][rg] + bias_n[ni];
      }
    }
  }
}

// ---------------------------------------------------------------------------
// Fallback fp32 MoE FFN kernels
// ---------------------------------------------------------------------------
__global__ __launch_bounds__(256) void moe_ffn1(
    const float* __restrict__ X, const int* __restrict__ list_tok,
    const float* __restrict__ W1, const float* __restrict__ B1,
    const int* __restrict__ cnt_used, const int* __restrict__ row_off,
    u16* __restrict__ Hbuf)
{
  const int e = blockIdx.z;
  const int cnt = cnt_used[e];
  const int m0 = blockIdx.x * 64;
  if (m0 >= cnt) return;
  const int n0 = blockIdx.y * 64;
  const float* W1e = W1 + (size_t)e * D_MODEL * D_FF;
  __shared__ float As[16][64];
  __shared__ float Bs[16][64];
  __shared__ int toks[64];
  const int t  = threadIdx.x;
  const int tx = t & 15, ty = t >> 4;
  const int r  = t >> 2, kq = t & 3;
  if (t < 64) toks[t] = (m0 + t < cnt) ? list_tok[e * CAP + m0 + t] : -1;
  __syncthreads();
  const int tok = toks[r];
  float acc[4][4] = {};
  for (int k0 = 0; k0 < D_MODEL; k0 += 16) {
    float4 a4 = make_float4(0.f, 0.f, 0.f, 0.f);
    if (tok >= 0)
      a4 = *(const float4*)&X[(size_t)tok * D_MODEL + k0 + kq * 4];
    float4 b4 = *(const float4*)&W1e[(size_t)(k0 + ty) * D_FF + n0 + tx * 4];
    __syncthreads();
    As[kq*4+0][r] = a4.x; As[kq*4+1][r] = a4.y;
    As[kq*4+2][r] = a4.z; As[kq*4+3][r] = a4.w;
    *(float4*)&Bs[ty][tx*4] = b4;
    __syncthreads();
#pragma unroll
    for (int k = 0; k < 16; ++k) {
      float4 av = *(const float4*)&As[k][ty*4];
      float4 bv = *(const float4*)&Bs[k][tx*4];
      float aa[4] = {av.x, av.y, av.z, av.w};
      float bb[4] = {bv.x, bv.y, bv.z, bv.w};
#pragma unroll
      for (int i = 0; i < 4; ++i)
#pragma unroll
        for (int j = 0; j < 4; ++j)
          acc[i][j] = fmaf(aa[i], bb[j], acc[i][j]);
    }
  }
  const int g0 = row_off[e];
  float4 bb4 = *(const float4*)&B1[(size_t)e * D_FF + n0 + tx*4];
  float bb[4] = {bb4.x, bb4.y, bb4.z, bb4.w};
#pragma unroll
  for (int i = 0; i < 4; ++i) {
    int m = m0 + ty*4 + i;
    if (m < cnt) {
      u16* hp = Hbuf + (size_t)(g0 + m) * D_FF + n0 + tx*4;
#pragma unroll
      for (int j = 0; j < 4; ++j) {
        float v = acc[i][j] + bb[j];
        v = 0.5f * v * (1.f + erff(v * 0.70710678118654752f));
        hp[j] = f32_to_bf16(v);
      }
    }
  }
}

__global__ __launch_bounds__(256) void moe_ffn2(
    const u16* __restrict__ Hbuf, const float* __restrict__ W2,
    const float* __restrict__ B2, const int* __restrict__ cnt_used,
    const int* __restrict__ row_off, float* __restrict__ Yexp)
{
  const int e = blockIdx.z;
  const int cnt = cnt_used[e];
  const int m0 = blockIdx.x * 64;
  if (m0 >= cnt) return;
  const int n0 = blockIdx.y * 64;
  const int g0 = row_off[e];
  const float* W2e = W2 + (size_t)e * D_FF * D_MODEL;
  __shared__ float As[16][64];
  __shared__ float Bs[16][64];
  const int t  = threadIdx.x;
  const int tx = t & 15, ty = t >> 4;
  const int r  = t >> 2, kq = t & 3;
  const bool rvalid = (m0 + r) < cnt;
  const u16* Hrow = Hbuf + (size_t)(g0 + m0 + r) * D_FF + kq * 4;
  float acc[4][4] = {};
  for (int k0 = 0; k0 < D_FF; k0 += 16) {
    float a0 = 0.f, a1 = 0.f, a2 = 0.f, a3 = 0.f;
    if (rvalid) {
      ushort4 hv = *(const ushort4*)(Hrow + k0);
      a0 = bf16_to_f32(hv.x); a1 = bf16_to_f32(hv.y);
      a2 = bf16_to_f32(hv.z); a3 = bf16_to_f32(hv.w);
    }
    float4 b4 = *(const float4*)&W2e[(size_t)(k0 + ty) * D_MODEL + n0 + tx * 4];
    __syncthreads();
    As[kq*4+0][r] = a0; As[kq*4+1][r] = a1;
    As[kq*4+2][r] = a2; As[kq*4+3][r] = a3;
    *(float4*)&Bs[ty][tx*4] = b4;
    __syncthreads();
#pragma unroll
    for (int k = 0; k < 16; ++k) {
      float4 av = *(const float4*)&As[k][ty*4];
      float4 bv = *(const float4*)&Bs[k][tx*4];
      float aa[4] = {av.x, av.y, av.z, av.w};
      float bb[4] = {bv.x, bv.y, bv.z, bv.w};
#pragma unroll
      for (int i = 0; i < 4; ++i)
#pragma unroll
        for (int j = 0; j < 4; ++j)
          acc[i][j] = fmaf(aa[i], bb[j], acc[i][j]);
    }
  }
  float4 bb4 = *(const float4*)&B2[(size_t)e * D_MODEL + n0 + tx*4];
#pragma unroll
  for (int i = 0; i < 4; ++i) {
    int m = m0 + ty*4 + i;
    if (m < cnt) {
      float4 o = {acc[i][0]+bb4.x, acc[i][1]+bb4.y, acc[i][2]+bb4.z, acc[i][3]+bb4.w};
      *(float4*)&Yexp[(size_t)(g0 + m) * D_MODEL + n0 + tx*4] = o;
    }
  }
}

// ---------------------------------------------------------------------------
// Combine + triple layernorm
// ---------------------------------------------------------------------------
__global__ __launch_bounds__(256) void moe_combine(
    const float* __restrict__ Yexp,
    const int* __restrict__ idx0, const int* __restrict__ idx1,
    const int* __restrict__ slot1, const int* __restrict__ slot2,
    const float* __restrict__ gate1, const float* __restrict__ gate2,
    const int* __restrict__ row_off, float* __restrict__ out)
{
  const int tkn = blockIdx.x;
  const int c = threadIdx.x * 4;
  float4 acc = {0.f, 0.f, 0.f, 0.f};
  int s1 = slot1[tkn];
  if (s1 >= 0) {
    int rr = row_off[idx0[tkn]] + s1;
    float g = gate1[tkn];
    float4 y = *(const float4*)&Yexp[(size_t)rr * D_MODEL + c];
    acc.x += g * y.x; acc.y += g * y.y; acc.z += g * y.z; acc.w += g * y.w;
  }
  int s2 = slot2[tkn];
  if (s2 >= 0) {
    int rr = row_off[idx1[tkn]] + s2;
    float g = gate2[tkn];
    float4 y = *(const float4*)&Yexp[(size_t)rr * D_MODEL + c];
    acc.x += g * y.x; acc.y += g * y.y; acc.z += g * y.z; acc.w += g * y.w;
  }
  *(float4*)&out[(size_t)tkn * D_MODEL + c] = acc;
}

__global__ __launch_bounds__(256) void ln_triple(
    float* __restrict__ out,
    const float* __restrict__ g1, const float* __restrict__ b1,
    const float* __restrict__ g2, const float* __restrict__ b2,
    const float* __restrict__ g3, const float* __restrict__ b3)
{
  const int row = blockIdx.x;
  const int t = threadIdx.x;
  __shared__ float red[12];
  float4 x = *(float4*)&out[(size_t)row * D_MODEL + t * 4];
  const float* gs[3] = {g1, g2, g3};
  const float* bs[3] = {b1, b2, b3};
#pragma unroll
  for (int p = 0; p < 3; ++p) {
    float s = x.x + x.y + x.z + x.w;
    float q = x.x*x.x + x.y*x.y + x.z*x.z + x.w*x.w;
#pragma unroll
    for (int off = 32; off > 0; off >>= 1) {
      s += __shfl_xor(s, off);
      q += __shfl_xor(q, off);
    }
    const int wave = t >> 6, lane = t & 63;
    if (lane == 0) { red[wave*2] = s; red[wave*2+1] = q; }
    __syncthreads();
    if (t == 0) {
      red[8] = red[0] + red[2] + red[4] + red[6];
      red[9] = red[1] + red[3] + red[5] + red[7];
    }
    __syncthreads();
    float mean = red[8] * (1.f / 1024.f);
    float var  = red[9] * (1.f / 1024.f) - mean * mean;
    float rinv = rsqrtf(var + LN_EPS);
    float4 gv = *(const float4*)&gs[p][t*4];
    float4 bv = *(const float4*)&bs[p][t*4];
    x.x = (x.x - mean) * rinv * gv.x + bv.x;
    x.y = (x.y - mean) * rinv * gv.y + bv.y;
    x.z = (x.z - mean) * rinv * gv.z + bv.z;
    x.w = (x.w - mean) * rinv * gv.w + bv.w;
    __syncthreads();
  }
  *(float4*)&out[(size_t)row * D_MODEL + t * 4] = x;
}

extern "C" void kernel_launch(void* const* d_in, const int* in_sizes, int n_in,
                              void* d_out, int out_size, void* d_ws, size_t ws_size,
                              hipStream_t stream) {
  (void)in_sizes; (void)n_in; (void)out_size;
  const float* tgt      = (const float*)d_in[0];
  const float* memory   = (const float*)d_in[1];
  const float* w_qkv_sa = (const float*)d_in[2];
  const float* b_qkv_sa = (const float*)d_in[3];
  const float* w_o_sa   = (const float*)d_in[4];
  const float* b_o_sa   = (const float*)d_in[5];
  const float* w_qkv_ca = (const float*)d_in[6];
  const float* b_qkv_ca = (const float*)d_in[7];
  const float* w_o_ca   = (const float*)d_in[8];
  const float* b_o_ca   = (const float*)d_in[9];
  const float* ln1g = (const float*)d_in[10];
  const float* ln1b = (const float*)d_in[11];
  const float* ln2g = (const float*)d_in[12];
  const float* ln2b = (const float*)d_in[13];
  const float* ln3g = (const float*)d_in[14];
  const float* ln3b = (const float*)d_in[15];
  const float* w_gate = (const float*)d_in[16];
  const float* w1  = (const float*)d_in[17];
  const float* b1e = (const float*)d_in[18];
  const float* w2  = (const float*)d_in[19];
  const float* b2e = (const float*)d_in[20];
  float* out = (float*)d_out;

  // Workspace layout (float offsets):
  //   [0, 12.58M)        B_qkv -> q2+kv2 -> Hbuf(lo)
  //   [12.58M, 16.78M)   B_ao           -> Hbuf(hi)
  //   [16.78M, 20.97M)   B_x1 -> Xg     -> Yexp(lo)
  //   [20.97M, 25.17M)   B_x2           -> Yexp(hi)
  //   [25.17M, 25.23M)   routing arrays
  //   [25.23M, 37.81M)   W' (attn weights, split-packed bf16)  -> W1T (after attn)
  //   [37.81M, 44.11M)   ACT' (activation split buffer)        -> W1T/W2T tail
  //   [42.01M, 58.79M)   W2T (after attention)
  float* ws     = (float*)d_ws;
  float* B_qkv  = ws;
  float* B_ao   = ws + 12582912;
  float* B_x1   = ws + 16777216;
  float* B_x2   = ws + 20971520;
  u16*   Hbuf   = (u16*)ws;
  float* Yexp   = B_x1;
  float* q2     = B_qkv;
  float* kv2    = B_qkv + 4194304;
  u16*   Xg     = (u16*)B_x1;
  u16*   Wp     = (u16*)(ws + 25231360);   // attn weights split-packed
  u16*   Wsa    = Wp;                       // 3072 rows
  u16*   Wosa   = Wp + 9437184;             // 1024 rows
  u16*   Wca    = Wp + 12582912;            // 3072 rows
  u16*   Woca   = Wp + 22020096;            // 1024 rows
  u16*   ACTp   = (u16*)(ws + 37814272);    // 4096 rows x 3072
  u16*   W1T    = (u16*)(ws + 25231360);
  u16*   W2T    = (u16*)(ws + 42008576);
  int*   idx0     = (int*)(ws + 25165824);
  int*   idx1     = idx0 + NTOK;
  int*   slot1    = idx1 + NTOK;
  int*   slot2    = slot1 + NTOK;
  int*   list_tok = slot2 + NTOK;
  int*   cnt_used = list_tok + N_EXP * CAP;
  int*   row_off  = cnt_used + N_EXP;
  float* gate1    = (float*)(row_off + N_EXP);
  float* gate2    = gate1 + NTOK;
  float* probsum  = gate2 + NTOK;

  const bool use_mfma = ws_size >= 235143168ull;  // 58,785,792 floats

  hipMemsetAsync(probsum, 0, N_EXP * sizeof(float), stream);

  if (use_mfma) {
    // weight split-pack (B-pattern)
    split_b<<<3072, 256, 0, stream>>>(w_qkv_sa, Wsa);
    split_b<<<1024, 256, 0, stream>>>(w_o_sa, Wosa);
    split_b<<<3072, 256, 0, stream>>>(w_qkv_ca, Wca);
    split_b<<<1024, 256, 0, stream>>>(w_o_ca, Woca);

    // ---- self attention ----
    split_a<<<4096, 256, 0, stream>>>(tgt, ACTp);
    gemm_x3<<<dim3(32, 24), 256, 0, stream>>>(ACTp, Wsa, b_qkv_sa, B_qkv, 3072);
    flash_mfma<<<dim3(8, 32), 256, 0, stream>>>(B_qkv, 3072, B_qkv + 1024, 3072,
                                                B_qkv + 2048, 3072, B_ao, 1024);
    split_a<<<4096, 256, 0, stream>>>(B_ao, ACTp);
    gemm_x3<<<dim3(32, 8), 256, 0, stream>>>(ACTp, Wosa, b_o_sa, B_x1, 1024);

    // ---- cross attention ----
    split_a<<<4096, 256, 0, stream>>>(B_x1, ACTp);
    gemm_x3<<<dim3(32, 8), 256, 0, stream>>>(ACTp, Wca, b_qkv_ca, q2, 1024);
    split_a<<<4096, 256, 0, stream>>>(memory, ACTp);
    gemm_x3<<<dim3(32, 16), 256, 0, stream>>>(ACTp, Wca + (size_t)1024 * 3072,
                                              b_qkv_ca + 1024, kv2, 2048);
    flash_mfma<<<dim3(8, 32), 256, 0, stream>>>(q2, 1024, kv2, 2048,
                                                kv2 + 1024, 2048, B_ao, 1024);
    split_a<<<4096, 256, 0, stream>>>(B_ao, ACTp);
    gemm_x3<<<dim3(32, 8), 256, 0, stream>>>(ACTp, Woca, b_o_ca, B_x2, 1024);
  } else {
    gemm_nt<<<dim3(64, 48), 256, 0, stream>>>(tgt, w_qkv_sa, b_qkv_sa, B_qkv, 3072, 1024);
    flash_attn<<<dim3(64, 32), 256, 0, stream>>>(B_qkv, 3072, B_qkv + 1024, 3072,
                                                 B_qkv + 2048, 3072, B_ao, 1024, 2048);
    gemm_nt<<<dim3(64, 16), 256, 0, stream>>>(B_ao, w_o_sa, b_o_sa, B_x1, 1024, 1024);
    gemm_nt<<<dim3(64, 16), 256, 0, stream>>>(B_x1, w_qkv_ca, b_qkv_ca, q2, 1024, 1024);
    gemm_nt<<<dim3(64, 32), 256, 0, stream>>>(memory, w_qkv_ca + (size_t)1024 * 1024,
                                              b_qkv_ca + 1024, kv2, 2048, 1024);
    flash_attn<<<dim3(64, 32), 256, 0, stream>>>(q2, 1024, kv2, 2048,
                                                 kv2 + 1024, 2048, B_ao, 1024, 2048);
    gemm_nt<<<dim3(64, 16), 256, 0, stream>>>(B_ao, w_o_ca, b_o_ca, B_x2, 1024, 1024);
  }

  // ---- MoE ----
  gate_topk<<<NTOK, 64, 0, stream>>>(B_x2, w_gate, idx0, idx1, gate1, gate2, probsum);
  route_scan<<<1, 512, 0, stream>>>(idx0, idx1, slot1, slot2, list_tok, cnt_used,
                                    row_off, probsum, out + (size_t)NTOK * D_MODEL);
  if (use_mfma) {
    transpose_bf16<<<dim3(128, 32, 8), 256, 0, stream>>>(w1, W1T, D_MODEL, D_FF);
    transpose_bf16<<<dim3(32, 128, 8), 256, 0, stream>>>(w2, W2T, D_FF, D_MODEL);
    moe_gather<<<dim3(CAP, 8), 256, 0, stream>>>(B_x2, list_tok, cnt_used, row_off, Xg);
    ffn1_mfma<<<dim3(16, 32, 8), 256, 0, stream>>>(Xg, W1T, b1e, cnt_used, row_off, Hbuf);
    ffn2_mfma<<<dim3(16, 8, 8), 256, 0, stream>>>(Hbuf, W2T, b2e, cnt_used, row_off, Yexp);
  } else {
    moe_ffn1<<<dim3(32, 64, 8), 256, 0, stream>>>(B_x2, list_tok, w1, b1e,
                                                  cnt_used, row_off, Hbuf);
    moe_ffn2<<<dim3(32, 16, 8), 256, 0, stream>>>(Hbuf, w2, b2e, cnt_used, row_off, Yexp);
  }
  moe_combine<<<NTOK, 256, 0, stream>>>(Yexp, idx0, idx1, slot1, slot2,
                                        gate1, gate2, row_off, out);

  // ---- 3x layernorm ----
  ln_triple<<<NTOK, 256, 0, stream>>>(out, ln1g, ln1b, ln2g, ln2b, ln3g, ln3b);
}